// Round 12
// baseline (307.232 us; speedup 1.0000x reference)
//
#include <hip/hip_runtime.h>
#include <math.h>

#define NN 50000
#define EPSM 1e-7f
#define BN_EPS 1e-5f
#define NBK 391                 // ceil(50000/128) buckets of 128 nodes
#define LOG2E 1.44269504088896340736f

// Reduction replication to kill cross-XCD atomic storms:
//   bn  : [32][256]  (block adds to replica blockIdx&31)
//   mm  : [8][128]   (replica blockIdx&7; [r][0:64)=colmin, [r][64:128)=colmax)
#define BN_REP 32
#define MM_REP 8

// native 2^x : v_exp_f32 (arg <= 0 here; FTZ for very negative arg is fine).
#if defined(__has_builtin)
#if __has_builtin(__builtin_amdgcn_exp2f)
#define HAVE_EXP2_BUILTIN 1
#endif
#endif
__device__ __forceinline__ float fast_exp2(float v){
#ifdef HAVE_EXP2_BUILTIN
  return __builtin_amdgcn_exp2f(v);
#else
  return exp2f(v);
#endif
}

// ---------------- bucket-sorted CSR build (line-coalesced writes) ----------------

__global__ __launch_bounds__(256) void bucket_hist_kernel(
    const int* __restrict__ dst, int* __restrict__ bhist, int E,
    unsigned* __restrict__ mm0, float* __restrict__ bn0){
  __shared__ int h[NBK];
  int t = threadIdx.x;
  if (blockIdx.x == 0){
    for (int i = t; i < 2 * MM_REP * 128; i += 256)
      mm0[i] = ((i & 127) < 64) ? 0x7F7FFFFFu : 0u;   // seeds mm0 AND mm1
    for (int i = t; i < 2 * BN_REP * 256; i += 256) bn0[i] = 0.f;  // bn0 AND bn1
  }
  for (int i = t; i < NBK; i += 256) h[i] = 0;
  __syncthreads();
  int e0 = blockIdx.x * 4096;
  int cnt = min(4096, E - e0);
  for (int i = t; i < cnt; i += 256) atomicAdd(&h[dst[e0 + i] >> 7], 1);
  __syncthreads();
  for (int i = t; i < NBK; i += 256) if (h[i]) atomicAdd(&bhist[i], h[i]);
}

__global__ void bucket_scan_kernel(const int* __restrict__ bhist,
                                   int* __restrict__ bbase, int* __restrict__ gcur){
  int lane = threadIdx.x;   // 64 threads
  int loc[7]; int s = 0;
#pragma unroll
  for (int k = 0; k < 7; ++k){
    int i = lane * 7 + k;
    int v = (i < NBK) ? bhist[i] : 0;
    loc[k] = s; s += v;
  }
  int sc = s;
#pragma unroll
  for (int o = 1; o < 64; o <<= 1){
    int n = __shfl_up(sc, o);
    if (lane >= o) sc += n;
  }
  int exc = sc - s;
#pragma unroll
  for (int k = 0; k < 7; ++k){
    int i = lane * 7 + k;
    if (i < NBK){ bbase[i] = exc + loc[k]; gcur[i] = exc + loc[k]; }
    else if (i == NBK) bbase[i] = exc + loc[k];   // total == E
  }
}

__global__ __launch_bounds__(256) void bucket_scatter_kernel(
    const int* __restrict__ src, const int* __restrict__ dst,
    int* __restrict__ gcur, unsigned* __restrict__ packed_g, int E){
  __shared__ int hist[NBK], offs[NBK], gb[NBK], curk[NBK];
  __shared__ unsigned stage[4096];
  __shared__ int gpos[4096];
  int t = threadIdx.x;
  for (int i = t; i < NBK; i += 256) hist[i] = 0;
  __syncthreads();
  int e0 = blockIdx.x * 4096;
  int cnt = min(4096, E - e0);
  unsigned pk[16]; int bk[16];
  int nmine = 0;
  for (int i = t; i < cnt; i += 256){
    int d = dst[e0 + i], s = src[e0 + i];
    pk[nmine] = ((unsigned)d << 16) | (unsigned)s;
    bk[nmine] = d >> 7;
    atomicAdd(&hist[bk[nmine]], 1);
    ++nmine;
  }
  __syncthreads();
  if (t < 64){                      // wave-0 scan of 391 counts (7 per lane)
    int loc[7]; int s = 0;
#pragma unroll
    for (int k = 0; k < 7; ++k){
      int i = t * 7 + k;
      int v = (i < NBK) ? hist[i] : 0;
      loc[k] = s; s += v;
    }
    int sc = s;
#pragma unroll
    for (int o = 1; o < 64; o <<= 1){
      int n = __shfl_up(sc, o);
      if (t >= o) sc += n;
    }
    int exc = sc - s;
#pragma unroll
    for (int k = 0; k < 7; ++k){
      int i = t * 7 + k;
      if (i < NBK) offs[i] = exc + loc[k];
    }
  }
  __syncthreads();
  for (int i = t; i < NBK; i += 256){
    int h = hist[i];
    gb[i] = h ? atomicAdd(&gcur[i], h) : 0;
    curk[i] = offs[i];
  }
  __syncthreads();
  for (int k = 0; k < nmine; ++k){
    int b = bk[k];
    int p = atomicAdd(&curk[b], 1);
    stage[p] = pk[k];
    gpos[p] = gb[b] + (p - offs[b]);
  }
  __syncthreads();
  for (int j = t; j < cnt; j += 256) packed_g[gpos[j]] = stage[j];   // run-coalesced
}

__global__ __launch_bounds__(256) void bucket_place_kernel(
    const unsigned* __restrict__ packed_g, const int* __restrict__ bbase,
    int* __restrict__ start_g, int* __restrict__ end_g,
    unsigned short* __restrict__ srcs_g, int N){
  __shared__ int deg[128], off[128], cur[128];
  __shared__ int sstage[4096];
  int b = blockIdx.x, t = threadIdx.x;
  int beg = bbase[b], cnt = bbase[b + 1] - beg;
  if (t < 128) deg[t] = 0;
  __syncthreads();
  for (int j = t; j < cnt; j += 256)
    atomicAdd(&deg[(packed_g[beg + j] >> 16) & 127], 1);
  __syncthreads();
  if (t < 64){                      // wave-0 scan of 128 (2 per lane)
    int i0 = t * 2;
    int v0 = deg[i0], v1 = deg[i0 + 1];
    int s = v0 + v1;
    int sc = s;
#pragma unroll
    for (int o = 1; o < 64; o <<= 1){
      int n = __shfl_up(sc, o);
      if (t >= o) sc += n;
    }
    int exc = sc - s;
    off[i0] = exc; off[i0 + 1] = exc + v0;
  }
  __syncthreads();
  int node0 = b * 128;
  if (t < 128){
    int node = node0 + t;
    if (node < N){
      start_g[node] = beg + off[t];
      end_g[node] = beg + off[t] + deg[t];
    }
    cur[t] = off[t];
  }
  __syncthreads();
  if (cnt <= 4096){
    for (int j = t; j < cnt; j += 256){
      unsigned p = packed_g[beg + j];
      int lp = atomicAdd(&cur[(p >> 16) & 127], 1);
      sstage[lp] = (int)(p & 0xFFFFu);
    }
    __syncthreads();
    for (int j = t; j < cnt; j += 256)
      srcs_g[beg + j] = (unsigned short)sstage[j];   // coalesced
  } else {                          // freak-bucket fallback (never for random graph)
    for (int j = t; j < cnt; j += 256){
      unsigned p = packed_g[beg + j];
      int lp = atomicAdd(&cur[(p >> 16) & 127], 1);
      srcs_g[beg + lp] = (unsigned short)(p & 0xFFFFu);
    }
  }
}

// ---------------- layer-0 only: bf16 message table [node][64] + column min/max ----

__global__ __launch_bounds__(256) void colminmax_kernel(
    const float* __restrict__ x, unsigned* __restrict__ mm,
    unsigned short* __restrict__ mh, int N){
  __shared__ unsigned smn[256], smx[256];
  int c = threadIdx.x & 63;
  int slot = blockIdx.x * 4 + (threadIdx.x >> 6);
  float mx = 0.f, mn = 1e30f;
  for (int r = slot; r < N; r += 256 * 4){
    float m = fmaxf(x[r * 64 + c], 0.f) + EPSM;
    unsigned u = __float_as_uint(m);
    u += 0x7FFFu + ((u >> 16) & 1u);         // RNE to bf16
    unsigned short us = (unsigned short)(u >> 16);
    mh[r * 64 + c] = us;
    float mb = __uint_as_float(((unsigned)us) << 16);
    mx = fmaxf(mx, mb);
    mn = fminf(mn, mb);
  }
  smn[threadIdx.x] = __float_as_uint(mn);
  smx[threadIdx.x] = __float_as_uint(mx);
  __syncthreads();
  if (threadIdx.x < 64){
    int rep = (blockIdx.x & (MM_REP - 1)) * 128;
    unsigned a = smn[c], b = smn[c + 64], d = smn[c + 128], e = smn[c + 192];
    atomicMin(&mm[rep + c], min(min(a, b), min(d, e)));
    a = smx[c]; b = smx[c + 64]; d = smx[c + 128]; e = smx[c + 192];
    atomicMax(&mm[rep + 64 + c], max(max(a, b), max(d, e)));
  }
}

// ------------- single-pass softmax aggregation -------------
// wave = 4 edge slots x 16 lanes; lane loads a uint2 = 4 bf16 channels. Native
// v_exp_f32 in exp2 domain; per-channel bound B from LDS (block-level reduce).

__global__ __launch_bounds__(256) void aggregate_kernel(
    const float* __restrict__ x, const uint2* __restrict__ mh2,
    const int* __restrict__ start, const int* __restrict__ segend,
    const unsigned short* __restrict__ srcs, const float* __restrict__ tptr,
    int layer, const unsigned* __restrict__ mm, float* __restrict__ h0, int N){
  __shared__ float4 Bs4[16];                // B[64] per-channel log2-domain bound
  int t = threadIdx.x;
  float t2 = tptr[layer] * LOG2E;
  if (t < 64){
    unsigned mn = 0x7F7FFFFFu, mx = 0u;     // positive floats: uint cmp == float cmp
#pragma unroll
    for (int r = 0; r < MM_REP; ++r){
      mn = min(mn, mm[r * 128 + t]);
      mx = max(mx, mm[r * 128 + 64 + t]);
    }
    ((float*)Bs4)[t] = fmaxf(t2 * __uint_as_float(mx), t2 * __uint_as_float(mn));
  }
  __syncthreads();
  int node = blockIdx.x * 4 + (t >> 6);
  if (node >= N) return;
  int lane = t & 63;
  int slot = lane >> 4, cp = lane & 15;     // channels 4cp .. 4cp+3
  float4 B = Bs4[cp];
  int beg = start[node], end = segend[node];
  float d0 = 0.f, d1 = 0.f, d2 = 0.f, d3 = 0.f;
  float n0 = 0.f, n1 = 0.f, n2 = 0.f, n3 = 0.f;
  int e = beg;
  for (; e + 7 < end; e += 8){              // 8 edges per wave-iteration
    int sA = srcs[e + slot];
    int sB = srcs[e + 4 + slot];
    uint2 uA = mh2[sA * 16 + cp];
    uint2 uB = mh2[sB * 16 + cp];
    float a0 = __uint_as_float(uA.x << 16), a1 = __uint_as_float(uA.x & 0xFFFF0000u);
    float a2 = __uint_as_float(uA.y << 16), a3 = __uint_as_float(uA.y & 0xFFFF0000u);
    float b0 = __uint_as_float(uB.x << 16), b1 = __uint_as_float(uB.x & 0xFFFF0000u);
    float b2 = __uint_as_float(uB.y << 16), b3 = __uint_as_float(uB.y & 0xFFFF0000u);
    float pA0 = fast_exp2(fmaf(a0, t2, -B.x)), pA1 = fast_exp2(fmaf(a1, t2, -B.y));
    float pA2 = fast_exp2(fmaf(a2, t2, -B.z)), pA3 = fast_exp2(fmaf(a3, t2, -B.w));
    float pB0 = fast_exp2(fmaf(b0, t2, -B.x)), pB1 = fast_exp2(fmaf(b1, t2, -B.y));
    float pB2 = fast_exp2(fmaf(b2, t2, -B.z)), pB3 = fast_exp2(fmaf(b3, t2, -B.w));
    d0 += pA0 + pB0; n0 += a0 * pA0 + b0 * pB0;
    d1 += pA1 + pB1; n1 += a1 * pA1 + b1 * pB1;
    d2 += pA2 + pB2; n2 += a2 * pA2 + b2 * pB2;
    d3 += pA3 + pB3; n3 += a3 * pA3 + b3 * pB3;
  }
  for (; e + slot < end; e += 4){           // tail: up to 7 edges
    int s = srcs[e + slot];
    uint2 u = mh2[s * 16 + cp];
    float a0 = __uint_as_float(u.x << 16), a1 = __uint_as_float(u.x & 0xFFFF0000u);
    float a2 = __uint_as_float(u.y << 16), a3 = __uint_as_float(u.y & 0xFFFF0000u);
    float p0 = fast_exp2(fmaf(a0, t2, -B.x)), p1 = fast_exp2(fmaf(a1, t2, -B.y));
    float p2 = fast_exp2(fmaf(a2, t2, -B.z)), p3 = fast_exp2(fmaf(a3, t2, -B.w));
    d0 += p0; n0 += a0 * p0;  d1 += p1; n1 += a1 * p1;
    d2 += p2; n2 += a2 * p2;  d3 += p3; n3 += a3 * p3;
  }
  d0 += __shfl_xor(d0, 16); d1 += __shfl_xor(d1, 16);
  d2 += __shfl_xor(d2, 16); d3 += __shfl_xor(d3, 16);
  n0 += __shfl_xor(n0, 16); n1 += __shfl_xor(n1, 16);
  n2 += __shfl_xor(n2, 16); n3 += __shfl_xor(n3, 16);
  d0 += __shfl_xor(d0, 32); d1 += __shfl_xor(d1, 32);
  d2 += __shfl_xor(d2, 32); d3 += __shfl_xor(d3, 32);
  n0 += __shfl_xor(n0, 32); n1 += __shfl_xor(n1, 32);
  n2 += __shfl_xor(n2, 32); n3 += __shfl_xor(n3, 32);
  if (slot == 0){
    float4 xv = ((const float4*)x)[node * 16 + cp];
    float4 o;
    o.x = n0 / (d0 + 1e-16f) + xv.x;
    o.y = n1 / (d1 + 1e-16f) + xv.y;
    o.z = n2 / (d2 + 1e-16f) + xv.z;
    o.w = n3 / (d3 + 1e-16f) + xv.w;
    ((float4*)h0)[node * 16 + cp] = o;
  }
}

// ---------------- MLP ----------------
// THIS ROUND: perfectly balanced grid — 250 blocks x 200 rows (250*200=50000),
// exactly 1 block per CU, max rows/CU 256 -> 200 (-22%). Every prior config
// had a 2:1 CU load imbalance (391 or 782 blocks on 256 CUs) with duration
// set by the 256-row CUs. Keeps 256t / unroll 2 / per-wave K rotation.

// h1 = h0 @ W1 + b1 ; fused BN sum/sumsq (replicated)
__global__ __launch_bounds__(256) void gemm1_kernel(
    const float* __restrict__ h0, const float* __restrict__ W1,
    const float* __restrict__ b1, float* __restrict__ h1,
    float* __restrict__ bn, int N){
  __shared__ float a_lds[200 * 68];         // 54.4 KB -> 1 block/CU (grid 250)
  int t = threadIdx.x;
  int row0 = blockIdx.x * 200;
  for (int li = t; li < 3200; li += 256){   // 200 rows x 16 float4
    int r = li >> 4, q = li & 15;
    int gr = row0 + r;
    float4 v = make_float4(0.f, 0.f, 0.f, 0.f);
    if (gr < N) v = ((const float4*)h0)[gr * 16 + q];
    *(float4*)&a_lds[r * 68 + q * 4] = v;
  }
  __syncthreads();
  int tc = t & 31, tr = t >> 5;             // tr 0..7 owns rows tr*25 .. tr*25+24
  float4 bias = ((const float4*)b1)[tc];
  float acc[25][4];
#pragma unroll
  for (int r = 0; r < 25; ++r){
    acc[r][0] = bias.x; acc[r][1] = bias.y; acc[r][2] = bias.z; acc[r][3] = bias.w;
  }
  const float4* wg = (const float4*)W1;     // [64][32] float4, L1/L2-resident
#pragma unroll 2
  for (int kk = 0; kk < 16; ++kk){
    int k = ((kk + (tr << 1)) & 15) << 2;   // per-wave rotated K order
    float4 w0 = wg[(k + 0) * 32 + tc];
    float4 w1 = wg[(k + 1) * 32 + tc];
    float4 w2 = wg[(k + 2) * 32 + tc];
    float4 w3 = wg[(k + 3) * 32 + tc];
#pragma unroll
    for (int r = 0; r < 25; ++r){
      float4 a = *(const float4*)&a_lds[(tr * 25 + r) * 68 + k];
      acc[r][0] += a.x * w0.x + a.y * w1.x + a.z * w2.x + a.w * w3.x;
      acc[r][1] += a.x * w0.y + a.y * w1.y + a.z * w2.y + a.w * w3.y;
      acc[r][2] += a.x * w0.z + a.y * w1.z + a.z * w2.z + a.w * w3.z;
      acc[r][3] += a.x * w0.w + a.y * w1.w + a.z * w2.w + a.w * w3.w;
    }
  }
  float s[4] = {0.f, 0.f, 0.f, 0.f}, s2[4] = {0.f, 0.f, 0.f, 0.f};
#pragma unroll
  for (int r = 0; r < 25; ++r){
    int gr = row0 + tr * 25 + r;
    if (gr < N){
      *(float4*)&h1[gr * 128 + tc * 4] =
          make_float4(acc[r][0], acc[r][1], acc[r][2], acc[r][3]);
#pragma unroll
      for (int j = 0; j < 4; ++j){ s[j] += acc[r][j]; s2[j] += acc[r][j] * acc[r][j]; }
    }
  }
  __syncthreads();
  float* red = a_lds;
  if (t < 256){ red[t] = 0.f; }
  __syncthreads();
#pragma unroll
  for (int j = 0; j < 4; ++j){
    atomicAdd(&red[tc * 4 + j], s[j]);
    atomicAdd(&red[128 + tc * 4 + j], s2[j]);
  }
  __syncthreads();
  if (t < 256) atomicAdd(&bn[(blockIdx.x & (BN_REP - 1)) * 256 + t], red[t]);
}

// xout = relu( relu(BN(h1)) @ W2 + b2 ). Layer 0 also emits next layer's bf16
// message table [node][64] and column min/max.
__global__ __launch_bounds__(256) void gemm2_kernel(
    const float* __restrict__ h1, const float* __restrict__ bn,
    const float* __restrict__ gamma, const float* __restrict__ beta, int layer,
    const float* __restrict__ W2, const float* __restrict__ b2,
    float* __restrict__ xout, int N,
    unsigned* __restrict__ mm_next, unsigned short* __restrict__ mh_next){
  __shared__ float a_lds[200 * 132];        // 105.6 KB -> 1 block/CU (grid 250)
  __shared__ float ss[256];                 // scale[128], shift[128]
  __shared__ unsigned smn[64], smx[64];
  int t = threadIdx.x;
  if (t < 128){
    float s = 0.f, s2 = 0.f;
#pragma unroll
    for (int r = 0; r < BN_REP; ++r){
      s  += bn[r * 256 + t];
      s2 += bn[r * 256 + 128 + t];
    }
    float mean = s * (1.f / (float)N);
    float var = s2 * (1.f / (float)N) - mean * mean;
    var = fmaxf(var, 0.f);
    float sc = gamma[layer * 128 + t] / sqrtf(var + BN_EPS);
    ss[t] = sc;
    ss[128 + t] = beta[layer * 128 + t] - mean * sc;
  }
  if (t < 64){ smn[t] = 0x7F7FFFFFu; smx[t] = 0u; }
  __syncthreads();
  int row0 = blockIdx.x * 200;
  for (int li = t; li < 6400; li += 256){   // 200 rows x 32 float4
    int r = li >> 5, q = li & 31;
    int gr = row0 + r;
    float4 v = make_float4(0.f, 0.f, 0.f, 0.f);
    if (gr < N) v = ((const float4*)h1)[gr * 32 + q];
    float4 sc = *(const float4*)&ss[q * 4];
    float4 sh = *(const float4*)&ss[128 + q * 4];
    v.x = fmaxf(v.x * sc.x + sh.x, 0.f);
    v.y = fmaxf(v.y * sc.y + sh.y, 0.f);
    v.z = fmaxf(v.z * sc.z + sh.z, 0.f);
    v.w = fmaxf(v.w * sc.w + sh.w, 0.f);
    *(float4*)&a_lds[r * 132 + q * 4] = v;
  }
  __syncthreads();
  // 16 row-groups over 200 rows: groups 0..7 own 13 rows, 8..15 own 12.
  int tc = t & 15, tr = t >> 4;
  int rbeg = tr * 12 + min(tr, 8);
  int rcnt = (tr < 8) ? 13 : 12;
  float4 bias = ((const float4*)b2)[tc];
  float acc[13][4];
#pragma unroll
  for (int r = 0; r < 13; ++r){
    acc[r][0] = bias.x; acc[r][1] = bias.y; acc[r][2] = bias.z; acc[r][3] = bias.w;
  }
  const float4* wg = (const float4*)W2;     // [128][16] float4, L1/L2-resident
#pragma unroll 2
  for (int kk = 0; kk < 32; ++kk){
    int k = ((kk + (tr << 1)) & 31) << 2;   // per-wave rotated K order
    float4 w0 = wg[(k + 0) * 16 + tc];
    float4 w1 = wg[(k + 1) * 16 + tc];
    float4 w2 = wg[(k + 2) * 16 + tc];
    float4 w3 = wg[(k + 3) * 16 + tc];
#pragma unroll
    for (int r = 0; r < 13; ++r){
      if (r < rcnt){
        float4 a = *(const float4*)&a_lds[(rbeg + r) * 132 + k];
        acc[r][0] += a.x * w0.x + a.y * w1.x + a.z * w2.x + a.w * w3.x;
        acc[r][1] += a.x * w0.y + a.y * w1.y + a.z * w2.y + a.w * w3.y;
        acc[r][2] += a.x * w0.z + a.y * w1.z + a.z * w2.z + a.w * w3.z;
        acc[r][3] += a.x * w0.w + a.y * w1.w + a.z * w2.w + a.w * w3.w;
      }
    }
  }
  unsigned mnv[4] = {0x7F7FFFFFu, 0x7F7FFFFFu, 0x7F7FFFFFu, 0x7F7FFFFFu};
  unsigned mxv[4] = {0u, 0u, 0u, 0u};
#pragma unroll
  for (int r = 0; r < 13; ++r){
    int gr = row0 + rbeg + r;
    if (r < rcnt && gr < N){
      float o0 = fmaxf(acc[r][0], 0.f), o1 = fmaxf(acc[r][1], 0.f);
      float o2 = fmaxf(acc[r][2], 0.f), o3 = fmaxf(acc[r][3], 0.f);
      *(float4*)&xout[gr * 64 + tc * 4] = make_float4(o0, o1, o2, o3);
      if (mh_next != 0){
        unsigned us[4];
        float ov[4] = {o0, o1, o2, o3};
#pragma unroll
        for (int j = 0; j < 4; ++j){
          unsigned u = __float_as_uint(ov[j] + EPSM);
          u += 0x7FFFu + ((u >> 16) & 1u);       // RNE to bf16
          us[j] = u >> 16;
          unsigned fb = us[j] << 16;              // rounded value bits (positive)
          mnv[j] = min(mnv[j], fb);
          mxv[j] = max(mxv[j], fb);
        }
        ((uint2*)mh_next)[gr * 16 + tc] =
            make_uint2(us[0] | (us[1] << 16), us[2] | (us[3] << 16));
      }
    }
  }
  if (mh_next != 0){
    __syncthreads();
#pragma unroll
    for (int j = 0; j < 4; ++j){
      atomicMin(&smn[tc * 4 + j], mnv[j]);
      atomicMax(&smx[tc * 4 + j], mxv[j]);
    }
    __syncthreads();
    if (t < 64){
      int rep = (blockIdx.x & (MM_REP - 1)) * 128;
      atomicMin(&mm_next[rep + t], smn[t]);
      atomicMax(&mm_next[rep + 64 + t], smx[t]);
    }
  }
}

extern "C" void kernel_launch(void* const* d_in, const int* in_sizes, int n_in,
                              void* d_out, int out_size, void* d_ws, size_t ws_size,
                              hipStream_t stream) {
  const float* x0    = (const float*)d_in[0];
  const int*   ei    = (const int*)d_in[1];
  const float* W1    = (const float*)d_in[2];
  const float* b1    = (const float*)d_in[3];
  const float* gamma = (const float*)d_in[4];
  const float* beta  = (const float*)d_in[5];
  const float* W2    = (const float*)d_in[6];
  const float* b2    = (const float*)d_in[7];
  const float* tptr  = (const float*)d_in[8];

  const int N = NN;
  const int E = in_sizes[1] / 2;
  const int* src = ei;
  const int* dst = ei + E;

  float* ws  = (float*)d_ws;
  float* h0  = ws;                        // N*64
  float* h1  = h0 + N * 64;               // N*128
  float* bn0 = h1 + N * 128;              // BN_REP*256
  float* bn1 = bn0 + BN_REP * 256;        // BN_REP*256
  unsigned* mm0 = (unsigned*)(bn1 + BN_REP * 256); // MM_REP*128
  unsigned* mm1 = mm0 + MM_REP * 128;              // MM_REP*128
  unsigned short* mh = (unsigned short*)(mm1 + MM_REP * 128);  // N*64 bf16, [node][64]
  int* bhist = (int*)(mh + N * 64);       // NBK
  int* bbase = bhist + NBK;               // NBK+1
  int* gcur  = bbase + NBK + 1;           // NBK
  int* start = gcur + NBK;                // N
  int* segend = start + N;                // N
  unsigned* packed = (unsigned*)(segend + N);  // E
  unsigned short* srcs = (unsigned short*)(packed + E);  // E

  float* out = (float*)d_out;

  const int row_blocks = (N + 199) / 200;      // 250 blocks x 200 rows = 1/CU
  const int chunk_blocks = (E + 4095) / 4096;
  const int agg_blocks = (N + 3) / 4;

  // ---- bucket-sorted CSR build (edge structure is layer-invariant) ----
  hipMemsetAsync(bhist, 0, NBK * sizeof(int), stream);
  bucket_hist_kernel<<<chunk_blocks, 256, 0, stream>>>(dst, bhist, E, mm0, bn0);
  bucket_scan_kernel<<<1, 64, 0, stream>>>(bhist, bbase, gcur);
  bucket_scatter_kernel<<<chunk_blocks, 256, 0, stream>>>(src, dst, gcur, packed, E);
  bucket_place_kernel<<<NBK, 256, 0, stream>>>(packed, bbase, start, segend, srcs, N);

  // ---- layer 0 ----
  colminmax_kernel<<<256, 256, 0, stream>>>(x0, mm0, mh, N);
  aggregate_kernel<<<agg_blocks, 256, 0, stream>>>(x0, (const uint2*)mh, start,
                                                   segend, srcs, tptr, 0, mm0, h0, N);
  gemm1_kernel<<<row_blocks, 256, 0, stream>>>(h0, W1, b1, h1, bn0, N);
  gemm2_kernel<<<row_blocks, 256, 0, stream>>>(h1, bn0, gamma, beta, 0, W2, b2,
                                               out, N, mm1, mh);
  // ---- layer 1 ----
  aggregate_kernel<<<agg_blocks, 256, 0, stream>>>(out, (const uint2*)mh, start,
                                                   segend, srcs, tptr, 1, mm1, h0, N);
  gemm1_kernel<<<row_blocks, 256, 0, stream>>>(h0, W1 + 8192, b1 + 128, h1, bn1, N);
  gemm2_kernel<<<row_blocks, 256, 0, stream>>>(h1, bn1, gamma, beta, 1, W2 + 8192,
                                               b2 + 64, out, N,
                                               (unsigned*)0, (unsigned short*)0);
}

// Round 13
// 296.021 us; speedup vs baseline: 1.0379x; 1.0379x over previous
//
#include <hip/hip_runtime.h>
#include <math.h>

#define NN 50000
#define EPSM 1e-7f
#define BN_EPS 1e-5f
#define NBK 391                 // ceil(50000/128) buckets of 128 nodes
#define LOG2E 1.44269504088896340736f

// Reduction replication to kill cross-XCD atomic storms:
//   bn  : [32][256]  (block adds to replica blockIdx&31)
//   mm  : [8][128]   (replica blockIdx&7; [r][0:64)=colmin, [r][64:128)=colmax)
#define BN_REP 32
#define MM_REP 8

// native 2^x : v_exp_f32 (arg <= 0 here; FTZ for very negative arg is fine).
#if defined(__has_builtin)
#if __has_builtin(__builtin_amdgcn_exp2f)
#define HAVE_EXP2_BUILTIN 1
#endif
#endif
__device__ __forceinline__ float fast_exp2(float v){
#ifdef HAVE_EXP2_BUILTIN
  return __builtin_amdgcn_exp2f(v);
#else
  return exp2f(v);
#endif
}

// ---------------- prep: fused colminmax (atomic-free) + bucket histogram ------
// 256 blocks. Every block streams its x-slice, emits bf16 message rows, and
// writes its OWN min/max row to mm256[block][128] (no atomics, no seeding
// dependency). Blocks < chunk_blocks also histogram their 4096-edge chunk
// (3.2 MB of dst hides under the 12.8 MB x stream).

__global__ __launch_bounds__(256) void prep_kernel(
    const float* __restrict__ x, unsigned short* __restrict__ mh,
    unsigned* __restrict__ mm256, int N,
    const int* __restrict__ dst, int* __restrict__ bhist, int E,
    int chunk_blocks){
  __shared__ unsigned smn[256], smx[256];
  __shared__ int h[NBK];
  int t = threadIdx.x;
  // ---- hist part (blocks 0..chunk_blocks-1) ----
  if (blockIdx.x < (unsigned)chunk_blocks){
    for (int i = t; i < NBK; i += 256) h[i] = 0;
    __syncthreads();
    int e0 = blockIdx.x * 4096;
    int cnt = min(4096, E - e0);
    for (int i = t; i < cnt; i += 256) atomicAdd(&h[dst[e0 + i] >> 7], 1);
    __syncthreads();
    for (int i = t; i < NBK; i += 256) if (h[i]) atomicAdd(&bhist[i], h[i]);
  }
  // ---- colminmax part (all blocks) ----
  int c = t & 63;
  int slot = blockIdx.x * 4 + (t >> 6);
  float mx = 0.f, mn = 1e30f;
  for (int r = slot; r < N; r += 256 * 4){
    float m = fmaxf(x[r * 64 + c], 0.f) + EPSM;
    unsigned u = __float_as_uint(m);
    u += 0x7FFFu + ((u >> 16) & 1u);         // RNE to bf16
    unsigned short us = (unsigned short)(u >> 16);
    mh[r * 64 + c] = us;
    float mb = __uint_as_float(((unsigned)us) << 16);
    mx = fmaxf(mx, mb);
    mn = fminf(mn, mb);
  }
  smn[t] = __float_as_uint(mn);
  smx[t] = __float_as_uint(mx);
  __syncthreads();
  if (t < 64){
    unsigned a = smn[c], b = smn[c + 64], d = smn[c + 128], e = smn[c + 192];
    mm256[blockIdx.x * 128 + c] = min(min(a, b), min(d, e));
    a = smx[c]; b = smx[c + 64]; d = smx[c + 128]; e = smx[c + 192];
    mm256[blockIdx.x * 128 + 64 + c] = max(max(a, b), max(d, e));
  }
}

// ---------------- scan: bucket exclusive scan + mm256 reduce + seeding --------
// 1 block x 256 threads. Wave 0: scan of 391 bucket counts. All threads:
// tree-reduce mm256[256][128] -> mm0 replica 0 (replicas 1..7 neutral), seed
// mm1 (8 neutral replicas), zero bn0/bn1. Min/max reduce is order-independent
// -> bit-identical to the old atomic scheme.

__global__ __launch_bounds__(256) void bucket_scan_kernel(
    const int* __restrict__ bhist, int* __restrict__ bbase,
    int* __restrict__ gcur, const unsigned* __restrict__ mm256,
    unsigned* __restrict__ mm0, unsigned* __restrict__ mm1,
    float* __restrict__ bn0){
  __shared__ unsigned sm[256];
  int t = threadIdx.x;
  if (t < 64){
    int loc[7]; int s = 0;
#pragma unroll
    for (int k = 0; k < 7; ++k){
      int i = t * 7 + k;
      int v = (i < NBK) ? bhist[i] : 0;
      loc[k] = s; s += v;
    }
    int sc = s;
#pragma unroll
    for (int o = 1; o < 64; o <<= 1){
      int n = __shfl_up(sc, o);
      if (t >= o) sc += n;
    }
    int exc = sc - s;
#pragma unroll
    for (int k = 0; k < 7; ++k){
      int i = t * 7 + k;
      if (i < NBK){ bbase[i] = exc + loc[k]; gcur[i] = exc + loc[k]; }
      else if (i == NBK) bbase[i] = exc + loc[k];   // total == E
    }
  }
  // mm256 reduce: thread t handles channel (t&127) over block-half (t>>7)
  int ch = t & 127, half = t >> 7;
  bool isMin = (ch < 64);
  unsigned v = isMin ? 0x7F7FFFFFu : 0u;
#pragma unroll 8
  for (int b = half * 128; b < half * 128 + 128; ++b){
    unsigned u = mm256[b * 128 + ch];
    v = isMin ? min(v, u) : max(v, u);
  }
  sm[t] = v;
  __syncthreads();
  if (t < 128){
    unsigned u0 = sm[t], u1 = sm[t + 128];
    mm0[t] = isMin ? min(u0, u1) : max(u0, u1);
  }
  // neutral-fill mm0 replicas 1..7 and all of mm1
  for (int i = t; i < MM_REP * 128; i += 256){
    unsigned neut = ((i & 127) < 64) ? 0x7F7FFFFFu : 0u;
    if (i >= 128) mm0[i] = neut;
    mm1[i] = neut;
  }
  // zero bn0 and bn1 (contiguous)
  for (int i = t; i < 2 * BN_REP * 256; i += 256) bn0[i] = 0.f;
}

// ---------------- bucket scatter / place (unchanged) ----------------

__global__ __launch_bounds__(256) void bucket_scatter_kernel(
    const int* __restrict__ src, const int* __restrict__ dst,
    int* __restrict__ gcur, unsigned* __restrict__ packed_g, int E){
  __shared__ int hist[NBK], offs[NBK], gb[NBK], curk[NBK];
  __shared__ unsigned stage[4096];
  __shared__ int gpos[4096];
  int t = threadIdx.x;
  for (int i = t; i < NBK; i += 256) hist[i] = 0;
  __syncthreads();
  int e0 = blockIdx.x * 4096;
  int cnt = min(4096, E - e0);
  unsigned pk[16]; int bk[16];
  int nmine = 0;
  for (int i = t; i < cnt; i += 256){
    int d = dst[e0 + i], s = src[e0 + i];
    pk[nmine] = ((unsigned)d << 16) | (unsigned)s;
    bk[nmine] = d >> 7;
    atomicAdd(&hist[bk[nmine]], 1);
    ++nmine;
  }
  __syncthreads();
  if (t < 64){                      // wave-0 scan of 391 counts (7 per lane)
    int loc[7]; int s = 0;
#pragma unroll
    for (int k = 0; k < 7; ++k){
      int i = t * 7 + k;
      int v = (i < NBK) ? hist[i] : 0;
      loc[k] = s; s += v;
    }
    int sc = s;
#pragma unroll
    for (int o = 1; o < 64; o <<= 1){
      int n = __shfl_up(sc, o);
      if (t >= o) sc += n;
    }
    int exc = sc - s;
#pragma unroll
    for (int k = 0; k < 7; ++k){
      int i = t * 7 + k;
      if (i < NBK) offs[i] = exc + loc[k];
    }
  }
  __syncthreads();
  for (int i = t; i < NBK; i += 256){
    int h = hist[i];
    gb[i] = h ? atomicAdd(&gcur[i], h) : 0;
    curk[i] = offs[i];
  }
  __syncthreads();
  for (int k = 0; k < nmine; ++k){
    int b = bk[k];
    int p = atomicAdd(&curk[b], 1);
    stage[p] = pk[k];
    gpos[p] = gb[b] + (p - offs[b]);
  }
  __syncthreads();
  for (int j = t; j < cnt; j += 256) packed_g[gpos[j]] = stage[j];   // run-coalesced
}

__global__ __launch_bounds__(256) void bucket_place_kernel(
    const unsigned* __restrict__ packed_g, const int* __restrict__ bbase,
    int* __restrict__ start_g, int* __restrict__ end_g,
    unsigned short* __restrict__ srcs_g, int N){
  __shared__ int deg[128], off[128], cur[128];
  __shared__ int sstage[4096];
  int b = blockIdx.x, t = threadIdx.x;
  int beg = bbase[b], cnt = bbase[b + 1] - beg;
  if (t < 128) deg[t] = 0;
  __syncthreads();
  for (int j = t; j < cnt; j += 256)
    atomicAdd(&deg[(packed_g[beg + j] >> 16) & 127], 1);
  __syncthreads();
  if (t < 64){                      // wave-0 scan of 128 (2 per lane)
    int i0 = t * 2;
    int v0 = deg[i0], v1 = deg[i0 + 1];
    int s = v0 + v1;
    int sc = s;
#pragma unroll
    for (int o = 1; o < 64; o <<= 1){
      int n = __shfl_up(sc, o);
      if (t >= o) sc += n;
    }
    int exc = sc - s;
    off[i0] = exc; off[i0 + 1] = exc + v0;
  }
  __syncthreads();
  int node0 = b * 128;
  if (t < 128){
    int node = node0 + t;
    if (node < N){
      start_g[node] = beg + off[t];
      end_g[node] = beg + off[t] + deg[t];
    }
    cur[t] = off[t];
  }
  __syncthreads();
  if (cnt <= 4096){
    for (int j = t; j < cnt; j += 256){
      unsigned p = packed_g[beg + j];
      int lp = atomicAdd(&cur[(p >> 16) & 127], 1);
      sstage[lp] = (int)(p & 0xFFFFu);
    }
    __syncthreads();
    for (int j = t; j < cnt; j += 256)
      srcs_g[beg + j] = (unsigned short)sstage[j];   // coalesced
  } else {                          // freak-bucket fallback (never for random graph)
    for (int j = t; j < cnt; j += 256){
      unsigned p = packed_g[beg + j];
      int lp = atomicAdd(&cur[(p >> 16) & 127], 1);
      srcs_g[beg + lp] = (unsigned short)(p & 0xFFFFu);
    }
  }
}

// ------------- single-pass softmax aggregation (unchanged, R11) -------------

__global__ __launch_bounds__(256) void aggregate_kernel(
    const float* __restrict__ x, const uint2* __restrict__ mh2,
    const int* __restrict__ start, const int* __restrict__ segend,
    const unsigned short* __restrict__ srcs, const float* __restrict__ tptr,
    int layer, const unsigned* __restrict__ mm, float* __restrict__ h0, int N){
  __shared__ float4 Bs4[16];                // B[64] per-channel log2-domain bound
  int t = threadIdx.x;
  float t2 = tptr[layer] * LOG2E;
  if (t < 64){
    unsigned mn = 0x7F7FFFFFu, mx = 0u;     // positive floats: uint cmp == float cmp
#pragma unroll
    for (int r = 0; r < MM_REP; ++r){
      mn = min(mn, mm[r * 128 + t]);
      mx = max(mx, mm[r * 128 + 64 + t]);
    }
    ((float*)Bs4)[t] = fmaxf(t2 * __uint_as_float(mx), t2 * __uint_as_float(mn));
  }
  __syncthreads();
  int node = blockIdx.x * 4 + (t >> 6);
  if (node >= N) return;
  int lane = t & 63;
  int slot = lane >> 4, cp = lane & 15;     // channels 4cp .. 4cp+3
  float4 B = Bs4[cp];
  int beg = start[node], end = segend[node];
  float d0 = 0.f, d1 = 0.f, d2 = 0.f, d3 = 0.f;
  float n0 = 0.f, n1 = 0.f, n2 = 0.f, n3 = 0.f;
  int e = beg;
  for (; e + 7 < end; e += 8){              // 8 edges per wave-iteration
    int sA = srcs[e + slot];
    int sB = srcs[e + 4 + slot];
    uint2 uA = mh2[sA * 16 + cp];
    uint2 uB = mh2[sB * 16 + cp];
    float a0 = __uint_as_float(uA.x << 16), a1 = __uint_as_float(uA.x & 0xFFFF0000u);
    float a2 = __uint_as_float(uA.y << 16), a3 = __uint_as_float(uA.y & 0xFFFF0000u);
    float b0 = __uint_as_float(uB.x << 16), b1 = __uint_as_float(uB.x & 0xFFFF0000u);
    float b2 = __uint_as_float(uB.y << 16), b3 = __uint_as_float(uB.y & 0xFFFF0000u);
    float pA0 = fast_exp2(fmaf(a0, t2, -B.x)), pA1 = fast_exp2(fmaf(a1, t2, -B.y));
    float pA2 = fast_exp2(fmaf(a2, t2, -B.z)), pA3 = fast_exp2(fmaf(a3, t2, -B.w));
    float pB0 = fast_exp2(fmaf(b0, t2, -B.x)), pB1 = fast_exp2(fmaf(b1, t2, -B.y));
    float pB2 = fast_exp2(fmaf(b2, t2, -B.z)), pB3 = fast_exp2(fmaf(b3, t2, -B.w));
    d0 += pA0 + pB0; n0 += a0 * pA0 + b0 * pB0;
    d1 += pA1 + pB1; n1 += a1 * pA1 + b1 * pB1;
    d2 += pA2 + pB2; n2 += a2 * pA2 + b2 * pB2;
    d3 += pA3 + pB3; n3 += a3 * pA3 + b3 * pB3;
  }
  for (; e + slot < end; e += 4){           // tail: up to 7 edges
    int s = srcs[e + slot];
    uint2 u = mh2[s * 16 + cp];
    float a0 = __uint_as_float(u.x << 16), a1 = __uint_as_float(u.x & 0xFFFF0000u);
    float a2 = __uint_as_float(u.y << 16), a3 = __uint_as_float(u.y & 0xFFFF0000u);
    float p0 = fast_exp2(fmaf(a0, t2, -B.x)), p1 = fast_exp2(fmaf(a1, t2, -B.y));
    float p2 = fast_exp2(fmaf(a2, t2, -B.z)), p3 = fast_exp2(fmaf(a3, t2, -B.w));
    d0 += p0; n0 += a0 * p0;  d1 += p1; n1 += a1 * p1;
    d2 += p2; n2 += a2 * p2;  d3 += p3; n3 += a3 * p3;
  }
  d0 += __shfl_xor(d0, 16); d1 += __shfl_xor(d1, 16);
  d2 += __shfl_xor(d2, 16); d3 += __shfl_xor(d3, 16);
  n0 += __shfl_xor(n0, 16); n1 += __shfl_xor(n1, 16);
  n2 += __shfl_xor(n2, 16); n3 += __shfl_xor(n3, 16);
  d0 += __shfl_xor(d0, 32); d1 += __shfl_xor(d1, 32);
  d2 += __shfl_xor(d2, 32); d3 += __shfl_xor(d3, 32);
  n0 += __shfl_xor(n0, 32); n1 += __shfl_xor(n1, 32);
  n2 += __shfl_xor(n2, 32); n3 += __shfl_xor(n3, 32);
  if (slot == 0){
    float4 xv = ((const float4*)x)[node * 16 + cp];
    float4 o;
    o.x = n0 / (d0 + 1e-16f) + xv.x;
    o.y = n1 / (d1 + 1e-16f) + xv.y;
    o.z = n2 / (d2 + 1e-16f) + xv.z;
    o.w = n3 / (d3 + 1e-16f) + xv.w;
    ((float4*)h0)[node * 16 + cp] = o;
  }
}

// ---------------- MLP (unchanged, R11-best: 128-row tiles, 256t, unroll 2,
// per-wave K rotation) ----------------

__global__ __launch_bounds__(256) void gemm1_kernel(
    const float* __restrict__ h0, const float* __restrict__ W1,
    const float* __restrict__ b1, float* __restrict__ h1,
    float* __restrict__ bn, int N){
  __shared__ float a_lds[128 * 68];         // 34.8 KB
  int t = threadIdx.x;
  int row0 = blockIdx.x * 128;
#pragma unroll
  for (int i = 0; i < 8; ++i){
    int li = t + 256 * i;
    int r = li >> 4, q = li & 15;
    int gr = row0 + r;
    float4 v = make_float4(0.f, 0.f, 0.f, 0.f);
    if (gr < N) v = ((const float4*)h0)[gr * 16 + q];
    *(float4*)&a_lds[r * 68 + q * 4] = v;
  }
  __syncthreads();
  int tc = t & 31, tr = t >> 5;             // tr 0..7 owns rows tr*16 .. tr*16+15
  float4 bias = ((const float4*)b1)[tc];
  float acc[16][4];
#pragma unroll
  for (int r = 0; r < 16; ++r){
    acc[r][0] = bias.x; acc[r][1] = bias.y; acc[r][2] = bias.z; acc[r][3] = bias.w;
  }
  const float4* wg = (const float4*)W1;     // [64][32] float4, L1/L2-resident
#pragma unroll 2
  for (int kk = 0; kk < 16; ++kk){
    int k = ((kk + (tr << 1)) & 15) << 2;   // per-wave rotated K order
    float4 w0 = wg[(k + 0) * 32 + tc];
    float4 w1 = wg[(k + 1) * 32 + tc];
    float4 w2 = wg[(k + 2) * 32 + tc];
    float4 w3 = wg[(k + 3) * 32 + tc];
#pragma unroll
    for (int r = 0; r < 16; ++r){
      float4 a = *(const float4*)&a_lds[(tr * 16 + r) * 68 + k];
      acc[r][0] += a.x * w0.x + a.y * w1.x + a.z * w2.x + a.w * w3.x;
      acc[r][1] += a.x * w0.y + a.y * w1.y + a.z * w2.y + a.w * w3.y;
      acc[r][2] += a.x * w0.z + a.y * w1.z + a.z * w2.z + a.w * w3.z;
      acc[r][3] += a.x * w0.w + a.y * w1.w + a.z * w2.w + a.w * w3.w;
    }
  }
  float s[4] = {0.f, 0.f, 0.f, 0.f}, s2[4] = {0.f, 0.f, 0.f, 0.f};
#pragma unroll
  for (int r = 0; r < 16; ++r){
    int gr = row0 + tr * 16 + r;
    if (gr < N){
      *(float4*)&h1[gr * 128 + tc * 4] =
          make_float4(acc[r][0], acc[r][1], acc[r][2], acc[r][3]);
#pragma unroll
      for (int j = 0; j < 4; ++j){ s[j] += acc[r][j]; s2[j] += acc[r][j] * acc[r][j]; }
    }
  }
  __syncthreads();
  float* red = a_lds;
  if (t < 256){ red[t] = 0.f; }
  __syncthreads();
#pragma unroll
  for (int j = 0; j < 4; ++j){
    atomicAdd(&red[tc * 4 + j], s[j]);
    atomicAdd(&red[128 + tc * 4 + j], s2[j]);
  }
  __syncthreads();
  if (t < 256) atomicAdd(&bn[(blockIdx.x & (BN_REP - 1)) * 256 + t], red[t]);
}

__global__ __launch_bounds__(256) void gemm2_kernel(
    const float* __restrict__ h1, const float* __restrict__ bn,
    const float* __restrict__ gamma, const float* __restrict__ beta, int layer,
    const float* __restrict__ W2, const float* __restrict__ b2,
    float* __restrict__ xout, int N,
    unsigned* __restrict__ mm_next, unsigned short* __restrict__ mh_next){
  __shared__ float a_lds[128 * 132];        // 67.6 KB -> 2 blocks/CU
  __shared__ float ss[256];                 // scale[128], shift[128]
  __shared__ unsigned smn[64], smx[64];
  int t = threadIdx.x;
  if (t < 128){
    float s = 0.f, s2 = 0.f;
#pragma unroll
    for (int r = 0; r < BN_REP; ++r){
      s  += bn[r * 256 + t];
      s2 += bn[r * 256 + 128 + t];
    }
    float mean = s * (1.f / (float)N);
    float var = s2 * (1.f / (float)N) - mean * mean;
    var = fmaxf(var, 0.f);
    float sc = gamma[layer * 128 + t] / sqrtf(var + BN_EPS);
    ss[t] = sc;
    ss[128 + t] = beta[layer * 128 + t] - mean * sc;
  }
  if (t < 64){ smn[t] = 0x7F7FFFFFu; smx[t] = 0u; }
  __syncthreads();
  int row0 = blockIdx.x * 128;
#pragma unroll
  for (int i = 0; i < 16; ++i){
    int li = t + 256 * i;
    int r = li >> 5, q = li & 31;
    int gr = row0 + r;
    float4 v = make_float4(0.f, 0.f, 0.f, 0.f);
    if (gr < N) v = ((const float4*)h1)[gr * 32 + q];
    float4 sc = *(const float4*)&ss[q * 4];
    float4 sh = *(const float4*)&ss[128 + q * 4];
    v.x = fmaxf(v.x * sc.x + sh.x, 0.f);
    v.y = fmaxf(v.y * sc.y + sh.y, 0.f);
    v.z = fmaxf(v.z * sc.z + sh.z, 0.f);
    v.w = fmaxf(v.w * sc.w + sh.w, 0.f);
    *(float4*)&a_lds[r * 132 + q * 4] = v;
  }
  __syncthreads();
  int tc = t & 15, tr = t >> 4;             // tr 0..15 owns rows tr*8 .. tr*8+7
  float4 bias = ((const float4*)b2)[tc];
  float acc[8][4];
#pragma unroll
  for (int r = 0; r < 8; ++r){
    acc[r][0] = bias.x; acc[r][1] = bias.y; acc[r][2] = bias.z; acc[r][3] = bias.w;
  }
  const float4* wg = (const float4*)W2;     // [128][16] float4, L1/L2-resident
#pragma unroll 2
  for (int kk = 0; kk < 32; ++kk){
    int k = ((kk + (tr << 1)) & 31) << 2;   // per-wave rotated K order
    float4 w0 = wg[(k + 0) * 16 + tc];
    float4 w1 = wg[(k + 1) * 16 + tc];
    float4 w2 = wg[(k + 2) * 16 + tc];
    float4 w3 = wg[(k + 3) * 16 + tc];
#pragma unroll
    for (int r = 0; r < 8; ++r){
      float4 a = *(const float4*)&a_lds[(tr * 8 + r) * 132 + k];
      acc[r][0] += a.x * w0.x + a.y * w1.x + a.z * w2.x + a.w * w3.x;
      acc[r][1] += a.x * w0.y + a.y * w1.y + a.z * w2.y + a.w * w3.y;
      acc[r][2] += a.x * w0.z + a.y * w1.z + a.z * w2.z + a.w * w3.z;
      acc[r][3] += a.x * w0.w + a.y * w1.w + a.z * w2.w + a.w * w3.w;
    }
  }
  unsigned mnv[4] = {0x7F7FFFFFu, 0x7F7FFFFFu, 0x7F7FFFFFu, 0x7F7FFFFFu};
  unsigned mxv[4] = {0u, 0u, 0u, 0u};
#pragma unroll
  for (int r = 0; r < 8; ++r){
    int gr = row0 + tr * 8 + r;
    if (gr < N){
      float o0 = fmaxf(acc[r][0], 0.f), o1 = fmaxf(acc[r][1], 0.f);
      float o2 = fmaxf(acc[r][2], 0.f), o3 = fmaxf(acc[r][3], 0.f);
      *(float4*)&xout[gr * 64 + tc * 4] = make_float4(o0, o1, o2, o3);
      if (mh_next != 0){
        unsigned us[4];
        float ov[4] = {o0, o1, o2, o3};
#pragma unroll
        for (int j = 0; j < 4; ++j){
          unsigned u = __float_as_uint(ov[j] + EPSM);
          u += 0x7FFFu + ((u >> 16) & 1u);       // RNE to bf16
          us[j] = u >> 16;
          unsigned fb = us[j] << 16;              // rounded value bits (positive)
          mnv[j] = min(mnv[j], fb);
          mxv[j] = max(mxv[j], fb);
        }
        ((uint2*)mh_next)[gr * 16 + tc] =
            make_uint2(us[0] | (us[1] << 16), us[2] | (us[3] << 16));
      }
    }
  }
  if (mh_next != 0){
    __syncthreads();
#pragma unroll
    for (int j = 0; j < 4; ++j){
      atomicMin(&smn[tc * 4 + j], mnv[j]);
      atomicMax(&smx[tc * 4 + j], mxv[j]);
    }
    __syncthreads();
    if (t < 64){
      int rep = (blockIdx.x & (MM_REP - 1)) * 128;
      atomicMin(&mm_next[rep + t], smn[t]);
      atomicMax(&mm_next[rep + 64 + t], smx[t]);
    }
  }
}

extern "C" void kernel_launch(void* const* d_in, const int* in_sizes, int n_in,
                              void* d_out, int out_size, void* d_ws, size_t ws_size,
                              hipStream_t stream) {
  const float* x0    = (const float*)d_in[0];
  const int*   ei    = (const int*)d_in[1];
  const float* W1    = (const float*)d_in[2];
  const float* b1    = (const float*)d_in[3];
  const float* gamma = (const float*)d_in[4];
  const float* beta  = (const float*)d_in[5];
  const float* W2    = (const float*)d_in[6];
  const float* b2    = (const float*)d_in[7];
  const float* tptr  = (const float*)d_in[8];

  const int N = NN;
  const int E = in_sizes[1] / 2;
  const int* src = ei;
  const int* dst = ei + E;

  float* ws  = (float*)d_ws;
  float* h0  = ws;                        // N*64
  float* h1  = h0 + N * 64;               // N*128
  float* bn0 = h1 + N * 128;              // BN_REP*256
  float* bn1 = bn0 + BN_REP * 256;        // BN_REP*256 (contiguous with bn0)
  unsigned* mm0 = (unsigned*)(bn1 + BN_REP * 256); // MM_REP*128
  unsigned* mm1 = mm0 + MM_REP * 128;              // MM_REP*128
  unsigned* mm256 = mm1 + MM_REP * 128;            // 256*128 block-own min/max
  unsigned short* mh = (unsigned short*)(mm256 + 256 * 128);  // N*64 bf16
  int* bhist = (int*)(mh + N * 64);       // NBK
  int* bbase = bhist + NBK;               // NBK+1
  int* gcur  = bbase + NBK + 1;           // NBK
  int* start = gcur + NBK;                // N
  int* segend = start + N;                // N
  unsigned* packed = (unsigned*)(segend + N);  // E
  unsigned short* srcs = (unsigned short*)(packed + E);  // E

  float* out = (float*)d_out;

  const int row_blocks = (N + 127) / 128;      // 391 for the 128-row gemm tiles
  const int chunk_blocks = (E + 4095) / 4096;
  const int agg_blocks = (N + 3) / 4;

  // ---- front-end: fused prep (colminmax + hist) -> scan (+reduce/seed) ----
  hipMemsetAsync(bhist, 0, NBK * sizeof(int), stream);
  prep_kernel<<<256, 256, 0, stream>>>(x0, mh, mm256, N, dst, bhist, E,
                                       chunk_blocks);
  bucket_scan_kernel<<<1, 256, 0, stream>>>(bhist, bbase, gcur, mm256,
                                            mm0, mm1, bn0);
  bucket_scatter_kernel<<<chunk_blocks, 256, 0, stream>>>(src, dst, gcur, packed, E);
  bucket_place_kernel<<<NBK, 256, 0, stream>>>(packed, bbase, start, segend, srcs, N);

  // ---- layer 0 ----
  aggregate_kernel<<<agg_blocks, 256, 0, stream>>>(x0, (const uint2*)mh, start,
                                                   segend, srcs, tptr, 0, mm0, h0, N);
  gemm1_kernel<<<row_blocks, 256, 0, stream>>>(h0, W1, b1, h1, bn0, N);
  gemm2_kernel<<<row_blocks, 256, 0, stream>>>(h1, bn0, gamma, beta, 0, W2, b2,
                                               out, N, mm1, mh);
  // ---- layer 1 ----
  aggregate_kernel<<<agg_blocks, 256, 0, stream>>>(out, (const uint2*)mh, start,
                                                   segend, srcs, tptr, 1, mm1, h0, N);
  gemm1_kernel<<<row_blocks, 256, 0, stream>>>(h0, W1 + 8192, b1 + 128, h1, bn1, N);
  gemm2_kernel<<<row_blocks, 256, 0, stream>>>(h1, bn1, gamma, beta, 1, W2 + 8192,
                                               b2 + 64, out, N,
                                               (unsigned*)0, (unsigned short*)0);
}

// Round 14
// 291.061 us; speedup vs baseline: 1.0556x; 1.0170x over previous
//
#include <hip/hip_runtime.h>
#include <math.h>

#define NN 50000
#define EPSM 1e-7f
#define BN_EPS 1e-5f
#define NBK 391                 // ceil(50000/128) buckets of 128 nodes
#define LOG2E 1.44269504088896340736f

// Reduction replication to kill cross-XCD atomic storms:
//   bn  : [32][256]  (block adds to replica blockIdx&31)
//   mm  : [8][128]   (replica blockIdx&7; [r][0:64)=colmin, [r][64:128)=colmax)
#define BN_REP 32
#define MM_REP 8

// native 2^x : v_exp_f32 (arg <= 0 here; FTZ for very negative arg is fine).
#if defined(__has_builtin)
#if __has_builtin(__builtin_amdgcn_exp2f)
#define HAVE_EXP2_BUILTIN 1
#endif
#endif
__device__ __forceinline__ float fast_exp2(float v){
#ifdef HAVE_EXP2_BUILTIN
  return __builtin_amdgcn_exp2f(v);
#else
  return exp2f(v);
#endif
}

// ---------------- bucket-sorted CSR build (line-coalesced writes) ----------------

__global__ __launch_bounds__(256) void bucket_hist_kernel(
    const int* __restrict__ dst, int* __restrict__ bhist, int E,
    unsigned* __restrict__ mm0, float* __restrict__ bn0){
  __shared__ int h[NBK];
  int t = threadIdx.x;
  if (blockIdx.x == 0){
    for (int i = t; i < 2 * MM_REP * 128; i += 256)
      mm0[i] = ((i & 127) < 64) ? 0x7F7FFFFFu : 0u;   // seeds mm0 AND mm1
    for (int i = t; i < 2 * BN_REP * 256; i += 256) bn0[i] = 0.f;  // bn0 AND bn1
  }
  for (int i = t; i < NBK; i += 256) h[i] = 0;
  __syncthreads();
  int e0 = blockIdx.x * 4096;
  int cnt = min(4096, E - e0);
  for (int i = t; i < cnt; i += 256) atomicAdd(&h[dst[e0 + i] >> 7], 1);
  __syncthreads();
  for (int i = t; i < NBK; i += 256) if (h[i]) atomicAdd(&bhist[i], h[i]);
}

__global__ void bucket_scan_kernel(const int* __restrict__ bhist,
                                   int* __restrict__ bbase, int* __restrict__ gcur){
  int lane = threadIdx.x;   // 64 threads
  int loc[7]; int s = 0;
#pragma unroll
  for (int k = 0; k < 7; ++k){
    int i = lane * 7 + k;
    int v = (i < NBK) ? bhist[i] : 0;
    loc[k] = s; s += v;
  }
  int sc = s;
#pragma unroll
  for (int o = 1; o < 64; o <<= 1){
    int n = __shfl_up(sc, o);
    if (lane >= o) sc += n;
  }
  int exc = sc - s;
#pragma unroll
  for (int k = 0; k < 7; ++k){
    int i = lane * 7 + k;
    if (i < NBK){ bbase[i] = exc + loc[k]; gcur[i] = exc + loc[k]; }
    else if (i == NBK) bbase[i] = exc + loc[k];   // total == E
  }
}

__global__ __launch_bounds__(256) void bucket_scatter_kernel(
    const int* __restrict__ src, const int* __restrict__ dst,
    int* __restrict__ gcur, unsigned* __restrict__ packed_g, int E){
  __shared__ int hist[NBK], offs[NBK], gb[NBK], curk[NBK];
  __shared__ unsigned stage[4096];
  __shared__ int gpos[4096];
  int t = threadIdx.x;
  for (int i = t; i < NBK; i += 256) hist[i] = 0;
  __syncthreads();
  int e0 = blockIdx.x * 4096;
  int cnt = min(4096, E - e0);
  unsigned pk[16]; int bk[16];
  int nmine = 0;
  for (int i = t; i < cnt; i += 256){
    int d = dst[e0 + i], s = src[e0 + i];
    pk[nmine] = ((unsigned)d << 16) | (unsigned)s;
    bk[nmine] = d >> 7;
    atomicAdd(&hist[bk[nmine]], 1);
    ++nmine;
  }
  __syncthreads();
  if (t < 64){                      // wave-0 scan of 391 counts (7 per lane)
    int loc[7]; int s = 0;
#pragma unroll
    for (int k = 0; k < 7; ++k){
      int i = t * 7 + k;
      int v = (i < NBK) ? hist[i] : 0;
      loc[k] = s; s += v;
    }
    int sc = s;
#pragma unroll
    for (int o = 1; o < 64; o <<= 1){
      int n = __shfl_up(sc, o);
      if (t >= o) sc += n;
    }
    int exc = sc - s;
#pragma unroll
    for (int k = 0; k < 7; ++k){
      int i = t * 7 + k;
      if (i < NBK) offs[i] = exc + loc[k];
    }
  }
  __syncthreads();
  for (int i = t; i < NBK; i += 256){
    int h = hist[i];
    gb[i] = h ? atomicAdd(&gcur[i], h) : 0;
    curk[i] = offs[i];
  }
  __syncthreads();
  for (int k = 0; k < nmine; ++k){
    int b = bk[k];
    int p = atomicAdd(&curk[b], 1);
    stage[p] = pk[k];
    gpos[p] = gb[b] + (p - offs[b]);
  }
  __syncthreads();
  for (int j = t; j < cnt; j += 256) packed_g[gpos[j]] = stage[j];   // run-coalesced
}

__global__ __launch_bounds__(256) void bucket_place_kernel(
    const unsigned* __restrict__ packed_g, const int* __restrict__ bbase,
    int* __restrict__ start_g, int* __restrict__ end_g,
    unsigned short* __restrict__ srcs_g, int N){
  __shared__ int deg[128], off[128], cur[128];
  __shared__ int sstage[4096];
  int b = blockIdx.x, t = threadIdx.x;
  int beg = bbase[b], cnt = bbase[b + 1] - beg;
  if (t < 128) deg[t] = 0;
  __syncthreads();
  for (int j = t; j < cnt; j += 256)
    atomicAdd(&deg[(packed_g[beg + j] >> 16) & 127], 1);
  __syncthreads();
  if (t < 64){                      // wave-0 scan of 128 (2 per lane)
    int i0 = t * 2;
    int v0 = deg[i0], v1 = deg[i0 + 1];
    int s = v0 + v1;
    int sc = s;
#pragma unroll
    for (int o = 1; o < 64; o <<= 1){
      int n = __shfl_up(sc, o);
      if (t >= o) sc += n;
    }
    int exc = sc - s;
    off[i0] = exc; off[i0 + 1] = exc + v0;
  }
  __syncthreads();
  int node0 = b * 128;
  if (t < 128){
    int node = node0 + t;
    if (node < N){
      start_g[node] = beg + off[t];
      end_g[node] = beg + off[t] + deg[t];
    }
    cur[t] = off[t];
  }
  __syncthreads();
  if (cnt <= 4096){
    for (int j = t; j < cnt; j += 256){
      unsigned p = packed_g[beg + j];
      int lp = atomicAdd(&cur[(p >> 16) & 127], 1);
      sstage[lp] = (int)(p & 0xFFFFu);
    }
    __syncthreads();
    for (int j = t; j < cnt; j += 256)
      srcs_g[beg + j] = (unsigned short)sstage[j];   // coalesced
  } else {                          // freak-bucket fallback (never for random graph)
    for (int j = t; j < cnt; j += 256){
      unsigned p = packed_g[beg + j];
      int lp = atomicAdd(&cur[(p >> 16) & 127], 1);
      srcs_g[beg + lp] = (unsigned short)(p & 0xFFFFu);
    }
  }
}

// ---------------- layer-0 only: bf16 message table [node][64] + column min/max ----

__global__ __launch_bounds__(256) void colminmax_kernel(
    const float* __restrict__ x, unsigned* __restrict__ mm,
    unsigned short* __restrict__ mh, int N){
  __shared__ unsigned smn[256], smx[256];
  int c = threadIdx.x & 63;
  int slot = blockIdx.x * 4 + (threadIdx.x >> 6);
  float mx = 0.f, mn = 1e30f;
  for (int r = slot; r < N; r += 256 * 4){
    float m = fmaxf(x[r * 64 + c], 0.f) + EPSM;
    unsigned u = __float_as_uint(m);
    u += 0x7FFFu + ((u >> 16) & 1u);         // RNE to bf16
    unsigned short us = (unsigned short)(u >> 16);
    mh[r * 64 + c] = us;
    float mb = __uint_as_float(((unsigned)us) << 16);
    mx = fmaxf(mx, mb);
    mn = fminf(mn, mb);
  }
  smn[threadIdx.x] = __float_as_uint(mn);
  smx[threadIdx.x] = __float_as_uint(mx);
  __syncthreads();
  if (threadIdx.x < 64){
    int rep = (blockIdx.x & (MM_REP - 1)) * 128;
    unsigned a = smn[c], b = smn[c + 64], d = smn[c + 128], e = smn[c + 192];
    atomicMin(&mm[rep + c], min(min(a, b), min(d, e)));
    a = smx[c]; b = smx[c + 64]; d = smx[c + 128]; e = smx[c + 192];
    atomicMax(&mm[rep + 64 + c], max(max(a, b), max(d, e)));
  }
}

// ------------- single-pass softmax aggregation -------------
// wave = 4 edge slots x 16 lanes; lane loads a uint2 = 4 bf16 channels. Native
// v_exp_f32 in exp2 domain; per-channel bound B from LDS (block-level reduce).

__global__ __launch_bounds__(256) void aggregate_kernel(
    const float* __restrict__ x, const uint2* __restrict__ mh2,
    const int* __restrict__ start, const int* __restrict__ segend,
    const unsigned short* __restrict__ srcs, const float* __restrict__ tptr,
    int layer, const unsigned* __restrict__ mm, float* __restrict__ h0, int N){
  __shared__ float4 Bs4[16];                // B[64] per-channel log2-domain bound
  int t = threadIdx.x;
  float t2 = tptr[layer] * LOG2E;
  if (t < 64){
    unsigned mn = 0x7F7FFFFFu, mx = 0u;     // positive floats: uint cmp == float cmp
#pragma unroll
    for (int r = 0; r < MM_REP; ++r){
      mn = min(mn, mm[r * 128 + t]);
      mx = max(mx, mm[r * 128 + 64 + t]);
    }
    ((float*)Bs4)[t] = fmaxf(t2 * __uint_as_float(mx), t2 * __uint_as_float(mn));
  }
  __syncthreads();
  int node = blockIdx.x * 4 + (t >> 6);
  if (node >= N) return;
  int lane = t & 63;
  int slot = lane >> 4, cp = lane & 15;     // channels 4cp .. 4cp+3
  float4 B = Bs4[cp];
  int beg = start[node], end = segend[node];
  float d0 = 0.f, d1 = 0.f, d2 = 0.f, d3 = 0.f;
  float n0 = 0.f, n1 = 0.f, n2 = 0.f, n3 = 0.f;
  int e = beg;
  for (; e + 7 < end; e += 8){              // 8 edges per wave-iteration
    int sA = srcs[e + slot];
    int sB = srcs[e + 4 + slot];
    uint2 uA = mh2[sA * 16 + cp];
    uint2 uB = mh2[sB * 16 + cp];
    float a0 = __uint_as_float(uA.x << 16), a1 = __uint_as_float(uA.x & 0xFFFF0000u);
    float a2 = __uint_as_float(uA.y << 16), a3 = __uint_as_float(uA.y & 0xFFFF0000u);
    float b0 = __uint_as_float(uB.x << 16), b1 = __uint_as_float(uB.x & 0xFFFF0000u);
    float b2 = __uint_as_float(uB.y << 16), b3 = __uint_as_float(uB.y & 0xFFFF0000u);
    float pA0 = fast_exp2(fmaf(a0, t2, -B.x)), pA1 = fast_exp2(fmaf(a1, t2, -B.y));
    float pA2 = fast_exp2(fmaf(a2, t2, -B.z)), pA3 = fast_exp2(fmaf(a3, t2, -B.w));
    float pB0 = fast_exp2(fmaf(b0, t2, -B.x)), pB1 = fast_exp2(fmaf(b1, t2, -B.y));
    float pB2 = fast_exp2(fmaf(b2, t2, -B.z)), pB3 = fast_exp2(fmaf(b3, t2, -B.w));
    d0 += pA0 + pB0; n0 += a0 * pA0 + b0 * pB0;
    d1 += pA1 + pB1; n1 += a1 * pA1 + b1 * pB1;
    d2 += pA2 + pB2; n2 += a2 * pA2 + b2 * pB2;
    d3 += pA3 + pB3; n3 += a3 * pA3 + b3 * pB3;
  }
  for (; e + slot < end; e += 4){           // tail: up to 7 edges
    int s = srcs[e + slot];
    uint2 u = mh2[s * 16 + cp];
    float a0 = __uint_as_float(u.x << 16), a1 = __uint_as_float(u.x & 0xFFFF0000u);
    float a2 = __uint_as_float(u.y << 16), a3 = __uint_as_float(u.y & 0xFFFF0000u);
    float p0 = fast_exp2(fmaf(a0, t2, -B.x)), p1 = fast_exp2(fmaf(a1, t2, -B.y));
    float p2 = fast_exp2(fmaf(a2, t2, -B.z)), p3 = fast_exp2(fmaf(a3, t2, -B.w));
    d0 += p0; n0 += a0 * p0;  d1 += p1; n1 += a1 * p1;
    d2 += p2; n2 += a2 * p2;  d3 += p3; n3 += a3 * p3;
  }
  d0 += __shfl_xor(d0, 16); d1 += __shfl_xor(d1, 16);
  d2 += __shfl_xor(d2, 16); d3 += __shfl_xor(d3, 16);
  n0 += __shfl_xor(n0, 16); n1 += __shfl_xor(n1, 16);
  n2 += __shfl_xor(n2, 16); n3 += __shfl_xor(n3, 16);
  d0 += __shfl_xor(d0, 32); d1 += __shfl_xor(d1, 32);
  d2 += __shfl_xor(d2, 32); d3 += __shfl_xor(d3, 32);
  n0 += __shfl_xor(n0, 32); n1 += __shfl_xor(n1, 32);
  n2 += __shfl_xor(n2, 32); n3 += __shfl_xor(n3, 32);
  if (slot == 0){
    float4 xv = ((const float4*)x)[node * 16 + cp];
    float4 o;
    o.x = n0 / (d0 + 1e-16f) + xv.x;
    o.y = n1 / (d1 + 1e-16f) + xv.y;
    o.z = n2 / (d2 + 1e-16f) + xv.z;
    o.w = n3 / (d3 + 1e-16f) + xv.w;
    ((float4*)h0)[node * 16 + cp] = o;
  }
}

// ---------------- MLP ----------------
// Locked best config (R11): 128-row tiles (halves total W-load instruction
// issue vs 64-row), 256 threads, unroll 2 (R8: full unroll spills; R9:
// unroll 4 neutral), per-wave K-offset rotation (decorrelates W streams).

// h1 = h0 @ W1 + b1 ; fused BN sum/sumsq (replicated)
__global__ __launch_bounds__(256) void gemm1_kernel(
    const float* __restrict__ h0, const float* __restrict__ W1,
    const float* __restrict__ b1, float* __restrict__ h1,
    float* __restrict__ bn, int N){
  __shared__ float a_lds[128 * 68];         // 34.8 KB
  int t = threadIdx.x;
  int row0 = blockIdx.x * 128;
#pragma unroll
  for (int i = 0; i < 8; ++i){
    int li = t + 256 * i;
    int r = li >> 4, q = li & 15;
    int gr = row0 + r;
    float4 v = make_float4(0.f, 0.f, 0.f, 0.f);
    if (gr < N) v = ((const float4*)h0)[gr * 16 + q];
    *(float4*)&a_lds[r * 68 + q * 4] = v;
  }
  __syncthreads();
  int tc = t & 31, tr = t >> 5;             // tr 0..7 owns rows tr*16 .. tr*16+15
  float4 bias = ((const float4*)b1)[tc];
  float acc[16][4];
#pragma unroll
  for (int r = 0; r < 16; ++r){
    acc[r][0] = bias.x; acc[r][1] = bias.y; acc[r][2] = bias.z; acc[r][3] = bias.w;
  }
  const float4* wg = (const float4*)W1;     // [64][32] float4, L1/L2-resident
#pragma unroll 2
  for (int kk = 0; kk < 16; ++kk){
    int k = ((kk + (tr << 1)) & 15) << 2;   // per-wave rotated K order
    float4 w0 = wg[(k + 0) * 32 + tc];
    float4 w1 = wg[(k + 1) * 32 + tc];
    float4 w2 = wg[(k + 2) * 32 + tc];
    float4 w3 = wg[(k + 3) * 32 + tc];
#pragma unroll
    for (int r = 0; r < 16; ++r){
      float4 a = *(const float4*)&a_lds[(tr * 16 + r) * 68 + k];
      acc[r][0] += a.x * w0.x + a.y * w1.x + a.z * w2.x + a.w * w3.x;
      acc[r][1] += a.x * w0.y + a.y * w1.y + a.z * w2.y + a.w * w3.y;
      acc[r][2] += a.x * w0.z + a.y * w1.z + a.z * w2.z + a.w * w3.z;
      acc[r][3] += a.x * w0.w + a.y * w1.w + a.z * w2.w + a.w * w3.w;
    }
  }
  float s[4] = {0.f, 0.f, 0.f, 0.f}, s2[4] = {0.f, 0.f, 0.f, 0.f};
#pragma unroll
  for (int r = 0; r < 16; ++r){
    int gr = row0 + tr * 16 + r;
    if (gr < N){
      *(float4*)&h1[gr * 128 + tc * 4] =
          make_float4(acc[r][0], acc[r][1], acc[r][2], acc[r][3]);
#pragma unroll
      for (int j = 0; j < 4; ++j){ s[j] += acc[r][j]; s2[j] += acc[r][j] * acc[r][j]; }
    }
  }
  __syncthreads();
  float* red = a_lds;
  if (t < 256){ red[t] = 0.f; }
  __syncthreads();
#pragma unroll
  for (int j = 0; j < 4; ++j){
    atomicAdd(&red[tc * 4 + j], s[j]);
    atomicAdd(&red[128 + tc * 4 + j], s2[j]);
  }
  __syncthreads();
  if (t < 256) atomicAdd(&bn[(blockIdx.x & (BN_REP - 1)) * 256 + t], red[t]);
}

// xout = relu( relu(BN(h1)) @ W2 + b2 ). Layer 0 also emits next layer's bf16
// message table [node][64] and column min/max.
__global__ __launch_bounds__(256) void gemm2_kernel(
    const float* __restrict__ h1, const float* __restrict__ bn,
    const float* __restrict__ gamma, const float* __restrict__ beta, int layer,
    const float* __restrict__ W2, const float* __restrict__ b2,
    float* __restrict__ xout, int N,
    unsigned* __restrict__ mm_next, unsigned short* __restrict__ mh_next){
  __shared__ float a_lds[128 * 132];        // 67.6 KB -> 2 blocks/CU
  __shared__ float ss[256];                 // scale[128], shift[128]
  __shared__ unsigned smn[64], smx[64];
  int t = threadIdx.x;
  if (t < 128){
    float s = 0.f, s2 = 0.f;
#pragma unroll
    for (int r = 0; r < BN_REP; ++r){
      s  += bn[r * 256 + t];
      s2 += bn[r * 256 + 128 + t];
    }
    float mean = s * (1.f / (float)N);
    float var = s2 * (1.f / (float)N) - mean * mean;
    var = fmaxf(var, 0.f);
    float sc = gamma[layer * 128 + t] / sqrtf(var + BN_EPS);
    ss[t] = sc;
    ss[128 + t] = beta[layer * 128 + t] - mean * sc;
  }
  if (t < 64){ smn[t] = 0x7F7FFFFFu; smx[t] = 0u; }
  __syncthreads();
  int row0 = blockIdx.x * 128;
#pragma unroll
  for (int i = 0; i < 16; ++i){
    int li = t + 256 * i;
    int r = li >> 5, q = li & 31;
    int gr = row0 + r;
    float4 v = make_float4(0.f, 0.f, 0.f, 0.f);
    if (gr < N) v = ((const float4*)h1)[gr * 32 + q];
    float4 sc = *(const float4*)&ss[q * 4];
    float4 sh = *(const float4*)&ss[128 + q * 4];
    v.x = fmaxf(v.x * sc.x + sh.x, 0.f);
    v.y = fmaxf(v.y * sc.y + sh.y, 0.f);
    v.z = fmaxf(v.z * sc.z + sh.z, 0.f);
    v.w = fmaxf(v.w * sc.w + sh.w, 0.f);
    *(float4*)&a_lds[r * 132 + q * 4] = v;
  }
  __syncthreads();
  int tc = t & 15, tr = t >> 4;             // tr 0..15 owns rows tr*8 .. tr*8+7
  float4 bias = ((const float4*)b2)[tc];
  float acc[8][4];
#pragma unroll
  for (int r = 0; r < 8; ++r){
    acc[r][0] = bias.x; acc[r][1] = bias.y; acc[r][2] = bias.z; acc[r][3] = bias.w;
  }
  const float4* wg = (const float4*)W2;     // [128][16] float4, L1/L2-resident
#pragma unroll 2
  for (int kk = 0; kk < 32; ++kk){
    int k = ((kk + (tr << 1)) & 31) << 2;   // per-wave rotated K order
    float4 w0 = wg[(k + 0) * 16 + tc];
    float4 w1 = wg[(k + 1) * 16 + tc];
    float4 w2 = wg[(k + 2) * 16 + tc];
    float4 w3 = wg[(k + 3) * 16 + tc];
#pragma unroll
    for (int r = 0; r < 8; ++r){
      float4 a = *(const float4*)&a_lds[(tr * 8 + r) * 132 + k];
      acc[r][0] += a.x * w0.x + a.y * w1.x + a.z * w2.x + a.w * w3.x;
      acc[r][1] += a.x * w0.y + a.y * w1.y + a.z * w2.y + a.w * w3.y;
      acc[r][2] += a.x * w0.z + a.y * w1.z + a.z * w2.z + a.w * w3.z;
      acc[r][3] += a.x * w0.w + a.y * w1.w + a.z * w2.w + a.w * w3.w;
    }
  }
  unsigned mnv[4] = {0x7F7FFFFFu, 0x7F7FFFFFu, 0x7F7FFFFFu, 0x7F7FFFFFu};
  unsigned mxv[4] = {0u, 0u, 0u, 0u};
#pragma unroll
  for (int r = 0; r < 8; ++r){
    int gr = row0 + tr * 8 + r;
    if (gr < N){
      float o0 = fmaxf(acc[r][0], 0.f), o1 = fmaxf(acc[r][1], 0.f);
      float o2 = fmaxf(acc[r][2], 0.f), o3 = fmaxf(acc[r][3], 0.f);
      *(float4*)&xout[gr * 64 + tc * 4] = make_float4(o0, o1, o2, o3);
      if (mh_next != 0){
        unsigned us[4];
        float ov[4] = {o0, o1, o2, o3};
#pragma unroll
        for (int j = 0; j < 4; ++j){
          unsigned u = __float_as_uint(ov[j] + EPSM);
          u += 0x7FFFu + ((u >> 16) & 1u);       // RNE to bf16
          us[j] = u >> 16;
          unsigned fb = us[j] << 16;              // rounded value bits (positive)
          mnv[j] = min(mnv[j], fb);
          mxv[j] = max(mxv[j], fb);
        }
        ((uint2*)mh_next)[gr * 16 + tc] =
            make_uint2(us[0] | (us[1] << 16), us[2] | (us[3] << 16));
      }
    }
  }
  if (mh_next != 0){
    __syncthreads();
#pragma unroll
    for (int j = 0; j < 4; ++j){
      atomicMin(&smn[tc * 4 + j], mnv[j]);
      atomicMax(&smx[tc * 4 + j], mxv[j]);
    }
    __syncthreads();
    if (t < 64){
      int rep = (blockIdx.x & (MM_REP - 1)) * 128;
      atomicMin(&mm_next[rep + t], smn[t]);
      atomicMax(&mm_next[rep + 64 + t], smx[t]);
    }
  }
}

extern "C" void kernel_launch(void* const* d_in, const int* in_sizes, int n_in,
                              void* d_out, int out_size, void* d_ws, size_t ws_size,
                              hipStream_t stream) {
  const float* x0    = (const float*)d_in[0];
  const int*   ei    = (const int*)d_in[1];
  const float* W1    = (const float*)d_in[2];
  const float* b1    = (const float*)d_in[3];
  const float* gamma = (const float*)d_in[4];
  const float* beta  = (const float*)d_in[5];
  const float* W2    = (const float*)d_in[6];
  const float* b2    = (const float*)d_in[7];
  const float* tptr  = (const float*)d_in[8];

  const int N = NN;
  const int E = in_sizes[1] / 2;
  const int* src = ei;
  const int* dst = ei + E;

  float* ws  = (float*)d_ws;
  float* h0  = ws;                        // N*64
  float* h1  = h0 + N * 64;               // N*128
  float* bn0 = h1 + N * 128;              // BN_REP*256
  float* bn1 = bn0 + BN_REP * 256;        // BN_REP*256
  unsigned* mm0 = (unsigned*)(bn1 + BN_REP * 256); // MM_REP*128
  unsigned* mm1 = mm0 + MM_REP * 128;              // MM_REP*128
  unsigned short* mh = (unsigned short*)(mm1 + MM_REP * 128);  // N*64 bf16, [node][64]
  int* bhist = (int*)(mh + N * 64);       // NBK
  int* bbase = bhist + NBK;               // NBK+1
  int* gcur  = bbase + NBK + 1;           // NBK
  int* start = gcur + NBK;                // N
  int* segend = start + N;                // N
  unsigned* packed = (unsigned*)(segend + N);  // E
  unsigned short* srcs = (unsigned short*)(packed + E);  // E

  float* out = (float*)d_out;

  const int row_blocks = (N + 127) / 128;      // 391 for the 128-row gemm tiles
  const int chunk_blocks = (E + 4095) / 4096;
  const int agg_blocks = (N + 3) / 4;

  // ---- bucket-sorted CSR build (edge structure is layer-invariant) ----
  hipMemsetAsync(bhist, 0, NBK * sizeof(int), stream);
  bucket_hist_kernel<<<chunk_blocks, 256, 0, stream>>>(dst, bhist, E, mm0, bn0);
  bucket_scan_kernel<<<1, 64, 0, stream>>>(bhist, bbase, gcur);
  bucket_scatter_kernel<<<chunk_blocks, 256, 0, stream>>>(src, dst, gcur, packed, E);
  bucket_place_kernel<<<NBK, 256, 0, stream>>>(packed, bbase, start, segend, srcs, N);

  // ---- layer 0 ----
  colminmax_kernel<<<256, 256, 0, stream>>>(x0, mm0, mh, N);
  aggregate_kernel<<<agg_blocks, 256, 0, stream>>>(x0, (const uint2*)mh, start,
                                                   segend, srcs, tptr, 0, mm0, h0, N);
  gemm1_kernel<<<row_blocks, 256, 0, stream>>>(h0, W1, b1, h1, bn0, N);
  gemm2_kernel<<<row_blocks, 256, 0, stream>>>(h1, bn0, gamma, beta, 0, W2, b2,
                                               out, N, mm1, mh);
  // ---- layer 1 ----
  aggregate_kernel<<<agg_blocks, 256, 0, stream>>>(out, (const uint2*)mh, start,
                                                   segend, srcs, tptr, 1, mm1, h0, N);
  gemm1_kernel<<<row_blocks, 256, 0, stream>>>(h0, W1 + 8192, b1 + 128, h1, bn1, N);
  gemm2_kernel<<<row_blocks, 256, 0, stream>>>(h1, bn1, gamma, beta, 1, W2 + 8192,
                                               b2 + 64, out, N,
                                               (unsigned*)0, (unsigned short*)0);
}

// Round 15
// 290.177 us; speedup vs baseline: 1.0588x; 1.0030x over previous
//
#include <hip/hip_runtime.h>
#include <math.h>

#define NN 50000
#define EPSM 1e-7f
#define BN_EPS 1e-5f
#define NBK 391                 // ceil(50000/128) buckets of 128 nodes
#define LOG2E 1.44269504088896340736f

// Reduction replication to kill cross-XCD atomic storms:
//   bn  : [32][256]  (block adds to replica blockIdx&31)
//   mm  : [8][128]   (replica blockIdx&7; [r][0:64)=colmin, [r][64:128)=colmax)
#define BN_REP 32
#define MM_REP 8

// native 2^x : v_exp_f32 (arg <= 0 here; FTZ for very negative arg is fine).
#if defined(__has_builtin)
#if __has_builtin(__builtin_amdgcn_exp2f)
#define HAVE_EXP2_BUILTIN 1
#endif
#endif
__device__ __forceinline__ float fast_exp2(float v){
#ifdef HAVE_EXP2_BUILTIN
  return __builtin_amdgcn_exp2f(v);
#else
  return exp2f(v);
#endif
}

// ---------------- bucket-sorted CSR build (line-coalesced writes) ----------------

__global__ __launch_bounds__(256) void bucket_hist_kernel(
    const int* __restrict__ dst, int* __restrict__ bhist, int E,
    unsigned* __restrict__ mm0, float* __restrict__ bn0){
  __shared__ int h[NBK];
  int t = threadIdx.x;
  if (blockIdx.x == 0){
    for (int i = t; i < 2 * MM_REP * 128; i += 256)
      mm0[i] = ((i & 127) < 64) ? 0x7F7FFFFFu : 0u;   // seeds mm0 AND mm1
    for (int i = t; i < 2 * BN_REP * 256; i += 256) bn0[i] = 0.f;  // bn0 AND bn1
  }
  for (int i = t; i < NBK; i += 256) h[i] = 0;
  __syncthreads();
  int e0 = blockIdx.x * 4096;
  int cnt = min(4096, E - e0);
  for (int i = t; i < cnt; i += 256) atomicAdd(&h[dst[e0 + i] >> 7], 1);
  __syncthreads();
  for (int i = t; i < NBK; i += 256) if (h[i]) atomicAdd(&bhist[i], h[i]);
}

__global__ void bucket_scan_kernel(const int* __restrict__ bhist,
                                   int* __restrict__ bbase, int* __restrict__ gcur){
  int lane = threadIdx.x;   // 64 threads
  int loc[7]; int s = 0;
#pragma unroll
  for (int k = 0; k < 7; ++k){
    int i = lane * 7 + k;
    int v = (i < NBK) ? bhist[i] : 0;
    loc[k] = s; s += v;
  }
  int sc = s;
#pragma unroll
  for (int o = 1; o < 64; o <<= 1){
    int n = __shfl_up(sc, o);
    if (lane >= o) sc += n;
  }
  int exc = sc - s;
#pragma unroll
  for (int k = 0; k < 7; ++k){
    int i = lane * 7 + k;
    if (i < NBK){ bbase[i] = exc + loc[k]; gcur[i] = exc + loc[k]; }
    else if (i == NBK) bbase[i] = exc + loc[k];   // total == E
  }
}

__global__ __launch_bounds__(256) void bucket_scatter_kernel(
    const int* __restrict__ src, const int* __restrict__ dst,
    int* __restrict__ gcur, unsigned* __restrict__ packed_g, int E){
  __shared__ int hist[NBK], offs[NBK], gb[NBK], curk[NBK];
  __shared__ unsigned stage[4096];
  __shared__ int gpos[4096];
  int t = threadIdx.x;
  for (int i = t; i < NBK; i += 256) hist[i] = 0;
  __syncthreads();
  int e0 = blockIdx.x * 4096;
  int cnt = min(4096, E - e0);
  unsigned pk[16]; int bk[16];
  int nmine = 0;
  for (int i = t; i < cnt; i += 256){
    int d = dst[e0 + i], s = src[e0 + i];
    pk[nmine] = ((unsigned)d << 16) | (unsigned)s;
    bk[nmine] = d >> 7;
    atomicAdd(&hist[bk[nmine]], 1);
    ++nmine;
  }
  __syncthreads();
  if (t < 64){                      // wave-0 scan of 391 counts (7 per lane)
    int loc[7]; int s = 0;
#pragma unroll
    for (int k = 0; k < 7; ++k){
      int i = t * 7 + k;
      int v = (i < NBK) ? hist[i] : 0;
      loc[k] = s; s += v;
    }
    int sc = s;
#pragma unroll
    for (int o = 1; o < 64; o <<= 1){
      int n = __shfl_up(sc, o);
      if (t >= o) sc += n;
    }
    int exc = sc - s;
#pragma unroll
    for (int k = 0; k < 7; ++k){
      int i = t * 7 + k;
      if (i < NBK) offs[i] = exc + loc[k];
    }
  }
  __syncthreads();
  for (int i = t; i < NBK; i += 256){
    int h = hist[i];
    gb[i] = h ? atomicAdd(&gcur[i], h) : 0;
    curk[i] = offs[i];
  }
  __syncthreads();
  for (int k = 0; k < nmine; ++k){
    int b = bk[k];
    int p = atomicAdd(&curk[b], 1);
    stage[p] = pk[k];
    gpos[p] = gb[b] + (p - offs[b]);
  }
  __syncthreads();
  for (int j = t; j < cnt; j += 256) packed_g[gpos[j]] = stage[j];   // run-coalesced
}

__global__ __launch_bounds__(256) void bucket_place_kernel(
    const unsigned* __restrict__ packed_g, const int* __restrict__ bbase,
    int* __restrict__ start_g, int* __restrict__ end_g,
    unsigned short* __restrict__ srcs_g, int N){
  __shared__ int deg[128], off[128], cur[128];
  __shared__ int sstage[4096];
  int b = blockIdx.x, t = threadIdx.x;
  int beg = bbase[b], cnt = bbase[b + 1] - beg;
  if (t < 128) deg[t] = 0;
  __syncthreads();
  for (int j = t; j < cnt; j += 256)
    atomicAdd(&deg[(packed_g[beg + j] >> 16) & 127], 1);
  __syncthreads();
  if (t < 64){                      // wave-0 scan of 128 (2 per lane)
    int i0 = t * 2;
    int v0 = deg[i0], v1 = deg[i0 + 1];
    int s = v0 + v1;
    int sc = s;
#pragma unroll
    for (int o = 1; o < 64; o <<= 1){
      int n = __shfl_up(sc, o);
      if (t >= o) sc += n;
    }
    int exc = sc - s;
    off[i0] = exc; off[i0 + 1] = exc + v0;
  }
  __syncthreads();
  int node0 = b * 128;
  if (t < 128){
    int node = node0 + t;
    if (node < N){
      start_g[node] = beg + off[t];
      end_g[node] = beg + off[t] + deg[t];
    }
    cur[t] = off[t];
  }
  __syncthreads();
  if (cnt <= 4096){
    for (int j = t; j < cnt; j += 256){
      unsigned p = packed_g[beg + j];
      int lp = atomicAdd(&cur[(p >> 16) & 127], 1);
      sstage[lp] = (int)(p & 0xFFFFu);
    }
    __syncthreads();
    for (int j = t; j < cnt; j += 256)
      srcs_g[beg + j] = (unsigned short)sstage[j];   // coalesced
  } else {                          // freak-bucket fallback (never for random graph)
    for (int j = t; j < cnt; j += 256){
      unsigned p = packed_g[beg + j];
      int lp = atomicAdd(&cur[(p >> 16) & 127], 1);
      srcs_g[beg + lp] = (unsigned short)(p & 0xFFFFu);
    }
  }
}

// ---------------- layer-0 only: bf16 message table [node][64] + column min/max ----

__global__ __launch_bounds__(256) void colminmax_kernel(
    const float* __restrict__ x, unsigned* __restrict__ mm,
    unsigned short* __restrict__ mh, int N){
  __shared__ unsigned smn[256], smx[256];
  int c = threadIdx.x & 63;
  int slot = blockIdx.x * 4 + (threadIdx.x >> 6);
  float mx = 0.f, mn = 1e30f;
  for (int r = slot; r < N; r += 256 * 4){
    float m = fmaxf(x[r * 64 + c], 0.f) + EPSM;
    unsigned u = __float_as_uint(m);
    u += 0x7FFFu + ((u >> 16) & 1u);         // RNE to bf16
    unsigned short us = (unsigned short)(u >> 16);
    mh[r * 64 + c] = us;
    float mb = __uint_as_float(((unsigned)us) << 16);
    mx = fmaxf(mx, mb);
    mn = fminf(mn, mb);
  }
  smn[threadIdx.x] = __float_as_uint(mn);
  smx[threadIdx.x] = __float_as_uint(mx);
  __syncthreads();
  if (threadIdx.x < 64){
    int rep = (blockIdx.x & (MM_REP - 1)) * 128;
    unsigned a = smn[c], b = smn[c + 64], d = smn[c + 128], e = smn[c + 192];
    atomicMin(&mm[rep + c], min(min(a, b), min(d, e)));
    a = smx[c]; b = smx[c + 64]; d = smx[c + 128]; e = smx[c + 192];
    atomicMax(&mm[rep + 64 + c], max(max(a, b), max(d, e)));
  }
}

// ------------- single-pass softmax aggregation -------------
// wave = 4 edge slots x 16 lanes; lane loads a uint2 = 4 bf16 channels. Native
// v_exp_f32 in exp2 domain; per-channel bound B from LDS (block-level reduce).

__global__ __launch_bounds__(256) void aggregate_kernel(
    const float* __restrict__ x, const uint2* __restrict__ mh2,
    const int* __restrict__ start, const int* __restrict__ segend,
    const unsigned short* __restrict__ srcs, const float* __restrict__ tptr,
    int layer, const unsigned* __restrict__ mm, float* __restrict__ h0, int N){
  __shared__ float4 Bs4[16];                // B[64] per-channel log2-domain bound
  int t = threadIdx.x;
  float t2 = tptr[layer] * LOG2E;
  if (t < 64){
    unsigned mn = 0x7F7FFFFFu, mx = 0u;     // positive floats: uint cmp == float cmp
#pragma unroll
    for (int r = 0; r < MM_REP; ++r){
      mn = min(mn, mm[r * 128 + t]);
      mx = max(mx, mm[r * 128 + 64 + t]);
    }
    ((float*)Bs4)[t] = fmaxf(t2 * __uint_as_float(mx), t2 * __uint_as_float(mn));
  }
  __syncthreads();
  int node = blockIdx.x * 4 + (t >> 6);
  if (node >= N) return;
  int lane = t & 63;
  int slot = lane >> 4, cp = lane & 15;     // channels 4cp .. 4cp+3
  float4 B = Bs4[cp];
  int beg = start[node], end = segend[node];
  float d0 = 0.f, d1 = 0.f, d2 = 0.f, d3 = 0.f;
  float n0 = 0.f, n1 = 0.f, n2 = 0.f, n3 = 0.f;
  int e = beg;
  for (; e + 7 < end; e += 8){              // 8 edges per wave-iteration
    int sA = srcs[e + slot];
    int sB = srcs[e + 4 + slot];
    uint2 uA = mh2[sA * 16 + cp];
    uint2 uB = mh2[sB * 16 + cp];
    float a0 = __uint_as_float(uA.x << 16), a1 = __uint_as_float(uA.x & 0xFFFF0000u);
    float a2 = __uint_as_float(uA.y << 16), a3 = __uint_as_float(uA.y & 0xFFFF0000u);
    float b0 = __uint_as_float(uB.x << 16), b1 = __uint_as_float(uB.x & 0xFFFF0000u);
    float b2 = __uint_as_float(uB.y << 16), b3 = __uint_as_float(uB.y & 0xFFFF0000u);
    float pA0 = fast_exp2(fmaf(a0, t2, -B.x)), pA1 = fast_exp2(fmaf(a1, t2, -B.y));
    float pA2 = fast_exp2(fmaf(a2, t2, -B.z)), pA3 = fast_exp2(fmaf(a3, t2, -B.w));
    float pB0 = fast_exp2(fmaf(b0, t2, -B.x)), pB1 = fast_exp2(fmaf(b1, t2, -B.y));
    float pB2 = fast_exp2(fmaf(b2, t2, -B.z)), pB3 = fast_exp2(fmaf(b3, t2, -B.w));
    d0 += pA0 + pB0; n0 += a0 * pA0 + b0 * pB0;
    d1 += pA1 + pB1; n1 += a1 * pA1 + b1 * pB1;
    d2 += pA2 + pB2; n2 += a2 * pA2 + b2 * pB2;
    d3 += pA3 + pB3; n3 += a3 * pA3 + b3 * pB3;
  }
  for (; e + slot < end; e += 4){           // tail: up to 7 edges
    int s = srcs[e + slot];
    uint2 u = mh2[s * 16 + cp];
    float a0 = __uint_as_float(u.x << 16), a1 = __uint_as_float(u.x & 0xFFFF0000u);
    float a2 = __uint_as_float(u.y << 16), a3 = __uint_as_float(u.y & 0xFFFF0000u);
    float p0 = fast_exp2(fmaf(a0, t2, -B.x)), p1 = fast_exp2(fmaf(a1, t2, -B.y));
    float p2 = fast_exp2(fmaf(a2, t2, -B.z)), p3 = fast_exp2(fmaf(a3, t2, -B.w));
    d0 += p0; n0 += a0 * p0;  d1 += p1; n1 += a1 * p1;
    d2 += p2; n2 += a2 * p2;  d3 += p3; n3 += a3 * p3;
  }
  d0 += __shfl_xor(d0, 16); d1 += __shfl_xor(d1, 16);
  d2 += __shfl_xor(d2, 16); d3 += __shfl_xor(d3, 16);
  n0 += __shfl_xor(n0, 16); n1 += __shfl_xor(n1, 16);
  n2 += __shfl_xor(n2, 16); n3 += __shfl_xor(n3, 16);
  d0 += __shfl_xor(d0, 32); d1 += __shfl_xor(d1, 32);
  d2 += __shfl_xor(d2, 32); d3 += __shfl_xor(d3, 32);
  n0 += __shfl_xor(n0, 32); n1 += __shfl_xor(n1, 32);
  n2 += __shfl_xor(n2, 32); n3 += __shfl_xor(n3, 32);
  if (slot == 0){
    float4 xv = ((const float4*)x)[node * 16 + cp];
    float4 o;
    o.x = n0 / (d0 + 1e-16f) + xv.x;
    o.y = n1 / (d1 + 1e-16f) + xv.y;
    o.z = n2 / (d2 + 1e-16f) + xv.z;
    o.w = n3 / (d3 + 1e-16f) + xv.w;
    ((float4*)h0)[node * 16 + cp] = o;
  }
}

// ---------------- MLP ----------------
// Locked best config (R11): 128-row tiles (halves total W-load instruction
// issue vs 64-row), 256 threads, unroll 2 (R8: full unroll spills; R9:
// unroll 4 neutral), per-wave K-offset rotation (decorrelates W streams).

// h1 = h0 @ W1 + b1 ; fused BN sum/sumsq (replicated)
__global__ __launch_bounds__(256) void gemm1_kernel(
    const float* __restrict__ h0, const float* __restrict__ W1,
    const float* __restrict__ b1, float* __restrict__ h1,
    float* __restrict__ bn, int N){
  __shared__ float a_lds[128 * 68];         // 34.8 KB
  int t = threadIdx.x;
  int row0 = blockIdx.x * 128;
#pragma unroll
  for (int i = 0; i < 8; ++i){
    int li = t + 256 * i;
    int r = li >> 4, q = li & 15;
    int gr = row0 + r;
    float4 v = make_float4(0.f, 0.f, 0.f, 0.f);
    if (gr < N) v = ((const float4*)h0)[gr * 16 + q];
    *(float4*)&a_lds[r * 68 + q * 4] = v;
  }
  __syncthreads();
  int tc = t & 31, tr = t >> 5;             // tr 0..7 owns rows tr*16 .. tr*16+15
  float4 bias = ((const float4*)b1)[tc];
  float acc[16][4];
#pragma unroll
  for (int r = 0; r < 16; ++r){
    acc[r][0] = bias.x; acc[r][1] = bias.y; acc[r][2] = bias.z; acc[r][3] = bias.w;
  }
  const float4* wg = (const float4*)W1;     // [64][32] float4, L1/L2-resident
#pragma unroll 2
  for (int kk = 0; kk < 16; ++kk){
    int k = ((kk + (tr << 1)) & 15) << 2;   // per-wave rotated K order
    float4 w0 = wg[(k + 0) * 32 + tc];
    float4 w1 = wg[(k + 1) * 32 + tc];
    float4 w2 = wg[(k + 2) * 32 + tc];
    float4 w3 = wg[(k + 3) * 32 + tc];
#pragma unroll
    for (int r = 0; r < 16; ++r){
      float4 a = *(const float4*)&a_lds[(tr * 16 + r) * 68 + k];
      acc[r][0] += a.x * w0.x + a.y * w1.x + a.z * w2.x + a.w * w3.x;
      acc[r][1] += a.x * w0.y + a.y * w1.y + a.z * w2.y + a.w * w3.y;
      acc[r][2] += a.x * w0.z + a.y * w1.z + a.z * w2.z + a.w * w3.z;
      acc[r][3] += a.x * w0.w + a.y * w1.w + a.z * w2.w + a.w * w3.w;
    }
  }
  float s[4] = {0.f, 0.f, 0.f, 0.f}, s2[4] = {0.f, 0.f, 0.f, 0.f};
#pragma unroll
  for (int r = 0; r < 16; ++r){
    int gr = row0 + tr * 16 + r;
    if (gr < N){
      *(float4*)&h1[gr * 128 + tc * 4] =
          make_float4(acc[r][0], acc[r][1], acc[r][2], acc[r][3]);
#pragma unroll
      for (int j = 0; j < 4; ++j){ s[j] += acc[r][j]; s2[j] += acc[r][j] * acc[r][j]; }
    }
  }
  __syncthreads();
  float* red = a_lds;
  if (t < 256){ red[t] = 0.f; }
  __syncthreads();
#pragma unroll
  for (int j = 0; j < 4; ++j){
    atomicAdd(&red[tc * 4 + j], s[j]);
    atomicAdd(&red[128 + tc * 4 + j], s2[j]);
  }
  __syncthreads();
  if (t < 256) atomicAdd(&bn[(blockIdx.x & (BN_REP - 1)) * 256 + t], red[t]);
}

// xout = relu( relu(BN(h1)) @ W2 + b2 ). Layer 0 also emits next layer's bf16
// message table [node][64] and column min/max.
__global__ __launch_bounds__(256) void gemm2_kernel(
    const float* __restrict__ h1, const float* __restrict__ bn,
    const float* __restrict__ gamma, const float* __restrict__ beta, int layer,
    const float* __restrict__ W2, const float* __restrict__ b2,
    float* __restrict__ xout, int N,
    unsigned* __restrict__ mm_next, unsigned short* __restrict__ mh_next){
  __shared__ float a_lds[128 * 132];        // 67.6 KB -> 2 blocks/CU
  __shared__ float ss[256];                 // scale[128], shift[128]
  __shared__ unsigned smn[64], smx[64];
  int t = threadIdx.x;
  if (t < 128){
    float s = 0.f, s2 = 0.f;
#pragma unroll
    for (int r = 0; r < BN_REP; ++r){
      s  += bn[r * 256 + t];
      s2 += bn[r * 256 + 128 + t];
    }
    float mean = s * (1.f / (float)N);
    float var = s2 * (1.f / (float)N) - mean * mean;
    var = fmaxf(var, 0.f);
    float sc = gamma[layer * 128 + t] / sqrtf(var + BN_EPS);
    ss[t] = sc;
    ss[128 + t] = beta[layer * 128 + t] - mean * sc;
  }
  if (t < 64){ smn[t] = 0x7F7FFFFFu; smx[t] = 0u; }
  __syncthreads();
  int row0 = blockIdx.x * 128;
#pragma unroll
  for (int i = 0; i < 16; ++i){
    int li = t + 256 * i;
    int r = li >> 5, q = li & 31;
    int gr = row0 + r;
    float4 v = make_float4(0.f, 0.f, 0.f, 0.f);
    if (gr < N) v = ((const float4*)h1)[gr * 32 + q];
    float4 sc = *(const float4*)&ss[q * 4];
    float4 sh = *(const float4*)&ss[128 + q * 4];
    v.x = fmaxf(v.x * sc.x + sh.x, 0.f);
    v.y = fmaxf(v.y * sc.y + sh.y, 0.f);
    v.z = fmaxf(v.z * sc.z + sh.z, 0.f);
    v.w = fmaxf(v.w * sc.w + sh.w, 0.f);
    *(float4*)&a_lds[r * 132 + q * 4] = v;
  }
  __syncthreads();
  int tc = t & 15, tr = t >> 4;             // tr 0..15 owns rows tr*8 .. tr*8+7
  float4 bias = ((const float4*)b2)[tc];
  float acc[8][4];
#pragma unroll
  for (int r = 0; r < 8; ++r){
    acc[r][0] = bias.x; acc[r][1] = bias.y; acc[r][2] = bias.z; acc[r][3] = bias.w;
  }
  const float4* wg = (const float4*)W2;     // [128][16] float4, L1/L2-resident
#pragma unroll 2
  for (int kk = 0; kk < 32; ++kk){
    int k = ((kk + (tr << 1)) & 31) << 2;   // per-wave rotated K order
    float4 w0 = wg[(k + 0) * 16 + tc];
    float4 w1 = wg[(k + 1) * 16 + tc];
    float4 w2 = wg[(k + 2) * 16 + tc];
    float4 w3 = wg[(k + 3) * 16 + tc];
#pragma unroll
    for (int r = 0; r < 8; ++r){
      float4 a = *(const float4*)&a_lds[(tr * 8 + r) * 132 + k];
      acc[r][0] += a.x * w0.x + a.y * w1.x + a.z * w2.x + a.w * w3.x;
      acc[r][1] += a.x * w0.y + a.y * w1.y + a.z * w2.y + a.w * w3.y;
      acc[r][2] += a.x * w0.z + a.y * w1.z + a.z * w2.z + a.w * w3.z;
      acc[r][3] += a.x * w0.w + a.y * w1.w + a.z * w2.w + a.w * w3.w;
    }
  }
  unsigned mnv[4] = {0x7F7FFFFFu, 0x7F7FFFFFu, 0x7F7FFFFFu, 0x7F7FFFFFu};
  unsigned mxv[4] = {0u, 0u, 0u, 0u};
#pragma unroll
  for (int r = 0; r < 8; ++r){
    int gr = row0 + tr * 8 + r;
    if (gr < N){
      float o0 = fmaxf(acc[r][0], 0.f), o1 = fmaxf(acc[r][1], 0.f);
      float o2 = fmaxf(acc[r][2], 0.f), o3 = fmaxf(acc[r][3], 0.f);
      *(float4*)&xout[gr * 64 + tc * 4] = make_float4(o0, o1, o2, o3);
      if (mh_next != 0){
        unsigned us[4];
        float ov[4] = {o0, o1, o2, o3};
#pragma unroll
        for (int j = 0; j < 4; ++j){
          unsigned u = __float_as_uint(ov[j] + EPSM);
          u += 0x7FFFu + ((u >> 16) & 1u);       // RNE to bf16
          us[j] = u >> 16;
          unsigned fb = us[j] << 16;              // rounded value bits (positive)
          mnv[j] = min(mnv[j], fb);
          mxv[j] = max(mxv[j], fb);
        }
        ((uint2*)mh_next)[gr * 16 + tc] =
            make_uint2(us[0] | (us[1] << 16), us[2] | (us[3] << 16));
      }
    }
  }
  if (mh_next != 0){
    __syncthreads();
#pragma unroll
    for (int j = 0; j < 4; ++j){
      atomicMin(&smn[tc * 4 + j], mnv[j]);
      atomicMax(&smx[tc * 4 + j], mxv[j]);
    }
    __syncthreads();
    if (t < 64){
      int rep = (blockIdx.x & (MM_REP - 1)) * 128;
      atomicMin(&mm_next[rep + t], smn[t]);
      atomicMax(&mm_next[rep + 64 + t], smx[t]);
    }
  }
}

extern "C" void kernel_launch(void* const* d_in, const int* in_sizes, int n_in,
                              void* d_out, int out_size, void* d_ws, size_t ws_size,
                              hipStream_t stream) {
  const float* x0    = (const float*)d_in[0];
  const int*   ei    = (const int*)d_in[1];
  const float* W1    = (const float*)d_in[2];
  const float* b1    = (const float*)d_in[3];
  const float* gamma = (const float*)d_in[4];
  const float* beta  = (const float*)d_in[5];
  const float* W2    = (const float*)d_in[6];
  const float* b2    = (const float*)d_in[7];
  const float* tptr  = (const float*)d_in[8];

  const int N = NN;
  const int E = in_sizes[1] / 2;
  const int* src = ei;
  const int* dst = ei + E;

  float* ws  = (float*)d_ws;
  float* h0  = ws;                        // N*64
  float* h1  = h0 + N * 64;               // N*128
  float* bn0 = h1 + N * 128;              // BN_REP*256
  float* bn1 = bn0 + BN_REP * 256;        // BN_REP*256
  unsigned* mm0 = (unsigned*)(bn1 + BN_REP * 256); // MM_REP*128
  unsigned* mm1 = mm0 + MM_REP * 128;              // MM_REP*128
  unsigned short* mh = (unsigned short*)(mm1 + MM_REP * 128);  // N*64 bf16, [node][64]
  int* bhist = (int*)(mh + N * 64);       // NBK
  int* bbase = bhist + NBK;               // NBK+1
  int* gcur  = bbase + NBK + 1;           // NBK
  int* start = gcur + NBK;                // N
  int* segend = start + N;                // N
  unsigned* packed = (unsigned*)(segend + N);  // E
  unsigned short* srcs = (unsigned short*)(packed + E);  // E

  float* out = (float*)d_out;

  const int row_blocks = (N + 127) / 128;      // 391 for the 128-row gemm tiles
  const int chunk_blocks = (E + 4095) / 4096;
  const int agg_blocks = (N + 3) / 4;

  // ---- bucket-sorted CSR build (edge structure is layer-invariant) ----
  hipMemsetAsync(bhist, 0, NBK * sizeof(int), stream);
  bucket_hist_kernel<<<chunk_blocks, 256, 0, stream>>>(dst, bhist, E, mm0, bn0);
  bucket_scan_kernel<<<1, 64, 0, stream>>>(bhist, bbase, gcur);
  bucket_scatter_kernel<<<chunk_blocks, 256, 0, stream>>>(src, dst, gcur, packed, E);
  bucket_place_kernel<<<NBK, 256, 0, stream>>>(packed, bbase, start, segend, srcs, N);

  // ---- layer 0 ----
  colminmax_kernel<<<256, 256, 0, stream>>>(x0, mm0, mh, N);
  aggregate_kernel<<<agg_blocks, 256, 0, stream>>>(x0, (const uint2*)mh, start,
                                                   segend, srcs, tptr, 0, mm0, h0, N);
  gemm1_kernel<<<row_blocks, 256, 0, stream>>>(h0, W1, b1, h1, bn0, N);
  gemm2_kernel<<<row_blocks, 256, 0, stream>>>(h1, bn0, gamma, beta, 0, W2, b2,
                                               out, N, mm1, mh);
  // ---- layer 1 ----
  aggregate_kernel<<<agg_blocks, 256, 0, stream>>>(out, (const uint2*)mh, start,
                                                   segend, srcs, tptr, 1, mm1, h0, N);
  gemm1_kernel<<<row_blocks, 256, 0, stream>>>(h0, W1 + 8192, b1 + 128, h1, bn1, N);
  gemm2_kernel<<<row_blocks, 256, 0, stream>>>(h1, bn1, gamma, beta, 1, W2 + 8192,
                                               b2 + 64, out, N,
                                               (unsigned*)0, (unsigned short*)0);
}